// Round 11
// baseline (1600.413 us; speedup 1.0000x reference)
//
#include <hip/hip_runtime.h>

#define B 128
#define S 16
#define E 512
#define R 1000
#define K3 1536
#define NW0 1920   // init worklist: 128 b * 15 pairs
#define NWS 256    // per-step worklist: 128 b * 2 entries
#define NS (B * (R + 1))
#define SCALE 0.04419417382415922f

static __device__ __forceinline__ float sigm(float x) { return 1.f / (1.f + expf(-x)); }

// ---------- block reductions (256 threads) ----------
static __device__ __forceinline__ float brsum(float v, float* sb) {
  int tid = threadIdx.x;
  sb[tid] = v; __syncthreads();
  for (int s = 128; s > 0; s >>= 1) {
    if (tid < s) sb[tid] += sb[tid + s];
    __syncthreads();
  }
  float r = sb[0]; __syncthreads();
  return r;
}
static __device__ __forceinline__ float brmax(float v, float* sb) {
  int tid = threadIdx.x;
  sb[tid] = v; __syncthreads();
  for (int s = 128; s > 0; s >>= 1) {
    if (tid < s) sb[tid] = fmaxf(sb[tid], sb[tid + s]);
    __syncthreads();
  }
  float r = sb[0]; __syncthreads();
  return r;
}
// paired sum reduction: (v1,v2) -> (sb[0], sb2[0])
static __device__ __forceinline__ void brsum2(float v1, float v2, float* sb, float* sb2,
                                              float* o1, float* o2) {
  int tid = threadIdx.x;
  sb[tid] = v1; sb2[tid] = v2; __syncthreads();
  for (int s = 128; s > 0; s >>= 1) {
    if (tid < s) { sb[tid] += sb[tid + s]; sb2[tid] += sb2[tid + s]; }
    __syncthreads();
  }
  *o1 = sb[0]; *o2 = sb2[0]; __syncthreads();
}

#define TILE_FMA \
  _Pragma("unroll") \
  for (int k = 0; k < 16; ++k) { \
    float4 a4 = *(const float4*)&As[k][ty * 4]; \
    float4 w4 = *(const float4*)&Ws[k][tx * 4]; \
    acc[0][0] = fmaf(a4.x, w4.x, acc[0][0]); acc[0][1] = fmaf(a4.x, w4.y, acc[0][1]); \
    acc[0][2] = fmaf(a4.x, w4.z, acc[0][2]); acc[0][3] = fmaf(a4.x, w4.w, acc[0][3]); \
    acc[1][0] = fmaf(a4.y, w4.x, acc[1][0]); acc[1][1] = fmaf(a4.y, w4.y, acc[1][1]); \
    acc[1][2] = fmaf(a4.y, w4.z, acc[1][2]); acc[1][3] = fmaf(a4.y, w4.w, acc[1][3]); \
    acc[2][0] = fmaf(a4.z, w4.x, acc[2][0]); acc[2][1] = fmaf(a4.z, w4.y, acc[2][1]); \
    acc[2][2] = fmaf(a4.z, w4.z, acc[2][2]); acc[2][3] = fmaf(a4.z, w4.w, acc[2][3]); \
    acc[3][0] = fmaf(a4.w, w4.x, acc[3][0]); acc[3][1] = fmaf(a4.w, w4.y, acc[3][1]); \
    acc[3][2] = fmaf(a4.w, w4.z, acc[3][2]); acc[3][3] = fmaf(a4.w, w4.w, acc[3][3]); \
  }

// 32-row-tile inner product: acc[2][4], A in As[16][32], W in Ws[16][64]
#define TILE_FMA32 \
  _Pragma("unroll") \
  for (int k = 0; k < 16; ++k) { \
    float2 a2 = *(const float2*)&As[k][ty * 2]; \
    float4 w4 = *(const float4*)&Ws[k][tx * 4]; \
    acc[0][0] = fmaf(a2.x, w4.x, acc[0][0]); acc[0][1] = fmaf(a2.x, w4.y, acc[0][1]); \
    acc[0][2] = fmaf(a2.x, w4.z, acc[0][2]); acc[0][3] = fmaf(a2.x, w4.w, acc[0][3]); \
    acc[1][0] = fmaf(a2.y, w4.x, acc[1][0]); acc[1][1] = fmaf(a2.y, w4.y, acc[1][1]); \
    acc[1][2] = fmaf(a2.y, w4.z, acc[1][2]); acc[1][3] = fmaf(a2.y, w4.w, acc[1][3]); \
  }

// ---------- 32-row single-output gemm (standalone): C = A.W^T + bias ----------
__global__ __launch_bounds__(256) void k_gemm32(const float* __restrict__ A, int lda, int M,
                                                const float* __restrict__ W, int N, int K,
                                                const float* __restrict__ bias,
                                                float* __restrict__ C, int ldc) {
  __shared__ float As[16][32];
  __shared__ float Ws[16][64];
  int tid = threadIdx.x;
  int mBase = blockIdx.y * 32;
  int nBase = blockIdx.x * 64;
  int tx = tid & 15, ty = tid >> 4;
  int ar = tid & 31, ak = (tid >> 5) * 2;
  int li = tid & 63, lk = (tid >> 6) * 4;
  float acc[2][4] = {{0.f,0.f,0.f,0.f},{0.f,0.f,0.f,0.f}};
  int m = mBase + ar;
  const float* Arow = (m < M) ? (A + (size_t)m * lda) : nullptr;
  int n = nBase + li;
  const float* Wrow = (n < N) ? (W + (size_t)n * K) : nullptr;
  float2 av = Arow ? *(const float2*)(Arow + ak) : make_float2(0.f, 0.f);
  float4 wv = Wrow ? *(const float4*)(Wrow + lk) : make_float4(0.f, 0.f, 0.f, 0.f);
  for (int k0 = 0; k0 < K; k0 += 16) {
    As[ak + 0][ar] = av.x; As[ak + 1][ar] = av.y;
    Ws[lk + 0][li] = wv.x; Ws[lk + 1][li] = wv.y;
    Ws[lk + 2][li] = wv.z; Ws[lk + 3][li] = wv.w;
    __syncthreads();
    if (k0 + 16 < K) {
      av = Arow ? *(const float2*)(Arow + k0 + 16 + ak) : make_float2(0.f, 0.f);
      wv = Wrow ? *(const float4*)(Wrow + k0 + 16 + lk) : make_float4(0.f, 0.f, 0.f, 0.f);
    }
    TILE_FMA32
    __syncthreads();
  }
#pragma unroll
  for (int r = 0; r < 2; ++r) {
    int mm = mBase + ty * 2 + r;
    if (mm >= M) continue;
#pragma unroll
    for (int c = 0; c < 4; ++c) {
      int nn = nBase + tx * 4 + c;
      if (nn >= N) continue;
      float v = acc[r][c];
      if (bias) v += bias[nn];
      C[(size_t)mm * ldc + nn] = v;
    }
  }
}

// ---------- 32-row dual-output gemm (standalone): n<N1 -> W1,b1,C1 ; else W2,C2 ----------
__global__ __launch_bounds__(256) void k_gemmD32(const float* __restrict__ A, int lda, int M,
                                                 const float* __restrict__ W1, int N1,
                                                 const float* __restrict__ b1,
                                                 float* __restrict__ C1, int ldc1,
                                                 const float* __restrict__ W2, int N2,
                                                 float* __restrict__ C2, int ldc2, int K) {
  __shared__ float As[16][32];
  __shared__ float Ws[16][64];
  int tid = threadIdx.x;
  int mBase = blockIdx.y * 32;
  int nBase = blockIdx.x * 64;
  int tx = tid & 15, ty = tid >> 4;
  int ar = tid & 31, ak = (tid >> 5) * 2;
  int li = tid & 63, lk = (tid >> 6) * 4;
  float acc[2][4] = {{0.f,0.f,0.f,0.f},{0.f,0.f,0.f,0.f}};
  int m = mBase + ar;
  const float* Arow = (m < M) ? (A + (size_t)m * lda) : nullptr;
  int n = nBase + li;
  const float* Wrow = nullptr;
  if (n < N1) Wrow = W1 + (size_t)n * K;
  else if (n < N1 + N2) Wrow = W2 + (size_t)(n - N1) * K;
  float2 av = Arow ? *(const float2*)(Arow + ak) : make_float2(0.f, 0.f);
  float4 wv = Wrow ? *(const float4*)(Wrow + lk) : make_float4(0.f, 0.f, 0.f, 0.f);
  for (int k0 = 0; k0 < K; k0 += 16) {
    As[ak + 0][ar] = av.x; As[ak + 1][ar] = av.y;
    Ws[lk + 0][li] = wv.x; Ws[lk + 1][li] = wv.y;
    Ws[lk + 2][li] = wv.z; Ws[lk + 3][li] = wv.w;
    __syncthreads();
    if (k0 + 16 < K) {
      av = Arow ? *(const float2*)(Arow + k0 + 16 + ak) : make_float2(0.f, 0.f);
      wv = Wrow ? *(const float4*)(Wrow + k0 + 16 + lk) : make_float4(0.f, 0.f, 0.f, 0.f);
    }
    TILE_FMA32
    __syncthreads();
  }
#pragma unroll
  for (int r = 0; r < 2; ++r) {
    int mm = mBase + ty * 2 + r;
    if (mm >= M) continue;
#pragma unroll
    for (int c = 0; c < 4; ++c) {
      int nn = nBase + tx * 4 + c;
      if (nn < N1) {
        float v = acc[r][c];
        if (b1) v += b1[nn];
        C1[(size_t)mm * ldc1 + nn] = v;
      } else if (nn < N1 + N2) {
        C2[(size_t)mm * ldc2 + (nn - N1)] = acc[r][c];
      }
    }
  }
}

// ---------- 64x64 gemm core for setup3 only ----------
static __device__ void dev_g64(float (*As)[64], float (*Ws)[64], int tid,
                               int mBase, int nBase,
                               const float* __restrict__ A, int lda, int M,
                               const float* __restrict__ W, int N, int K,
                               const float* __restrict__ bias, float scale,
                               float* __restrict__ C, int ldc) {
  int tx = tid & 15, ty = tid >> 4;
  int li = tid & 63;
  int lk = (tid >> 6) * 4;
  float acc[4][4] = {{0.f,0.f,0.f,0.f},{0.f,0.f,0.f,0.f},{0.f,0.f,0.f,0.f},{0.f,0.f,0.f,0.f}};
  int m = mBase + li;
  const float* Arow = (m < M) ? (A + (size_t)m * lda) : nullptr;
  int n = nBase + li;
  const float* Wrow = (n < N) ? (W + (size_t)n * K) : nullptr;

  float4 av = Arow ? *(const float4*)(Arow + lk) : make_float4(0.f, 0.f, 0.f, 0.f);
  float4 wv = Wrow ? *(const float4*)(Wrow + lk) : make_float4(0.f, 0.f, 0.f, 0.f);

  for (int k0 = 0; k0 < K; k0 += 16) {
    As[lk + 0][li] = av.x; As[lk + 1][li] = av.y;
    As[lk + 2][li] = av.z; As[lk + 3][li] = av.w;
    Ws[lk + 0][li] = wv.x; Ws[lk + 1][li] = wv.y;
    Ws[lk + 2][li] = wv.z; Ws[lk + 3][li] = wv.w;
    __syncthreads();
    if (k0 + 16 < K) {
      av = Arow ? *(const float4*)(Arow + k0 + 16 + lk) : make_float4(0.f, 0.f, 0.f, 0.f);
      wv = Wrow ? *(const float4*)(Wrow + k0 + 16 + lk) : make_float4(0.f, 0.f, 0.f, 0.f);
    }
    TILE_FMA
    __syncthreads();
  }
#pragma unroll
  for (int r = 0; r < 4; ++r) {
    int mm = mBase + ty * 4 + r;
    if (mm >= M) continue;
#pragma unroll
    for (int c = 0; c < 4; ++c) {
      int nn = nBase + tx * 4 + c;
      if (nn >= N) continue;
      float v = acc[r][c] * scale;
      if (bias) v += bias[nn];
      C[(size_t)mm * ldc + nn] = v;
    }
  }
}

// ---------- 64x64 transpose tile (device) ----------
static __device__ void dev_tr64(float (*t)[65], int tid, const float* __restrict__ src,
                                int Cc, float* __restrict__ dst, int ldd, int bx, int by) {
  int tx = tid & 15, ty = tid >> 4;
  int rb = by * 64, cb = bx * 64;
#pragma unroll
  for (int i = 0; i < 4; ++i) {
    int r = rb + ty + i * 16;
    float4 v = *(const float4*)(src + (size_t)r * Cc + cb + tx * 4);
    t[ty + i * 16][tx * 4 + 0] = v.x; t[ty + i * 16][tx * 4 + 1] = v.y;
    t[ty + i * 16][tx * 4 + 2] = v.z; t[ty + i * 16][tx * 4 + 3] = v.w;
  }
  __syncthreads();
#pragma unroll
  for (int i = 0; i < 4; ++i) {
    int c = cb + ty + i * 16;
    float4 v;
    v.x = t[tx * 4 + 0][ty + i * 16]; v.y = t[tx * 4 + 1][ty + i * 16];
    v.z = t[tx * 4 + 2][ty + i * 16]; v.w = t[tx * 4 + 3][ty + i * 16];
    *(float4*)(dst + (size_t)c * ldd + rb + tx * 4) = v;
  }
}

// ---------- setup L1: transposes + initwl + Wbig pad + out col14 zero ----------
__global__ __launch_bounds__(256) void k_prep(const float* __restrict__ Wq,
                                              const float* __restrict__ Wk,
                                              const float* __restrict__ Wih,
                                              float* __restrict__ WqT,
                                              float* __restrict__ WkT,
                                              float* __restrict__ Wbig,
                                              int* __restrict__ pos,
                                              int* __restrict__ wlb,
                                              int* __restrict__ wlL,
                                              int* __restrict__ wlR,
                                              float* __restrict__ outp) {
  __shared__ float t[64][65];
  int blk = blockIdx.x, tid = threadIdx.x;
  if (blk < 64) {
    dev_tr64(t, tid, Wq, E, WqT, E, blk & 7, blk >> 3);
  } else if (blk < 128) {
    int j = blk - 64;
    dev_tr64(t, tid, Wk, E, WkT, E, j & 7, j >> 3);
  } else if (blk < 320) {
    int j = blk - 128;
    dev_tr64(t, tid, Wih, E, Wbig + (size_t)1024 * K3, K3, j & 7, j >> 3);
  } else if (blk < 328) {
    int idx = (blk - 320) * 256 + tid;
    if (idx < B * 16) pos[idx] = idx & 15;
    if (idx < NW0) {
      wlb[idx] = idx / 15;
      int i = idx % 15;
      wlL[idx] = i;
      wlR[idx] = i + 1;
    }
    if (idx < B) outp[NS + idx * 16 + 14] = 0.f;  // loss col 14 is identically 0
  } else {
    int idx = (blk - 328) * 256 + tid;
    for (int i = idx; i < 24 * K3; i += 8 * 256) Wbig[(size_t)1000 * K3 + i] = 0.f;
  }
}

// ---------- setup L3: G2 gemm [0,128), Mqk gemm [128,192), misc [192,199) ----------
__global__ __launch_bounds__(256) void k_setup3(const float* __restrict__ KREL,
                                                const float* __restrict__ WqT,
                                                const float* __restrict__ WkT,
                                                const float* __restrict__ bq,
                                                const float* __restrict__ bk,
                                                float* __restrict__ Gbig,
                                                float* __restrict__ v12,
                                                float* __restrict__ c0s,
                                                float* __restrict__ gb) {
  __shared__ float As[16][64];
  __shared__ float Ws[16][64];
  int blk = blockIdx.x, tid = threadIdx.x;
  if (blk < 128) {
    dev_g64(As, Ws, tid, (blk >> 3) * 64, (blk & 7) * 64, KREL, E, R, WqT, E, E,
            nullptr, 1.f, Gbig, E);
  } else if (blk < 192) {
    int j = blk - 128;
    dev_g64(As, Ws, tid, (j >> 3) * 64, (j & 7) * 64, WqT, E, E, WkT, E, E,
            nullptr, 1.f, Gbig + (size_t)1000 * E, E);
  } else {
    int m = blk - 192;
    if (m < 2) {
      int i = m * 256 + tid;
      const float* wq = WqT + (size_t)i * E;
      const float* wk = WkT + (size_t)i * E;
      float s = 0.f;
      for (int e = 0; e < E; ++e) s += wq[e] * bk[e] + bq[e] * wk[e];
      v12[i] = s;
    } else if (m == 2) {
      float* sb = (float*)As;
      float p = 0.f;
      for (int e = tid; e < E; e += 256) p += bq[e] * bk[e];
      float s = brsum(p, sb);
      if (tid == 0) c0s[0] = s;
    } else {
      int r = (m - 3) * 256 + tid;
      if (r < R) {
        const float* kr = KREL + (size_t)r * E;
        float s = 0.f;
        for (int e = 0; e < E; ++e) s += bq[e] * kr[e];
        gb[r] = s;
      }
    }
  }
}

// ---------- GI init gather (+ fused h1 for setup worklist) + SCT pre-init ----------
__global__ __launch_bounds__(256) void k_giinit(const int* __restrict__ tokens,
                                                const float* __restrict__ Wbig,
                                                const float* __restrict__ bih,
                                                float* __restrict__ GI,
                                                const float* __restrict__ gb,
                                                float* __restrict__ SCT,
                                                const float* __restrict__ bhh,
                                                float* __restrict__ H1C) {
  int row = blockIdx.x, tid = threadIdx.x;
  if (row < B * S) {
    int tok = tokens[row];
    const float4* src = (const float4*)(Wbig + (size_t)tok * K3);
    const float4* bv = (const float4*)bih;
    float* girow = GI + (size_t)row * K3;
    float4* dst = (float4*)girow;
    for (int i = tid; i < K3 / 4; i += 256) {
      float4 a = src[i], b = bv[i];
      dst[i] = make_float4(a.x + b.x, a.y + b.y, a.z + b.z, a.w + b.w);
    }
    int i16 = row & 15;
    if (i16 < 15) {  // fused h1 for worklist entry w = (row>>4)*15 + i16
      __syncthreads();  // GI row visible (this block's own writes)
      float* h = H1C + (size_t)((row >> 4) * 15 + i16) * E;
      for (int e = tid; e < E; e += 256) {
        float r = sigm(girow[e] + bhh[e]);
        float z = sigm(girow[E + e] + bhh[E + e]);
        h[e] = (1.f - z) * tanhf(girow[2 * E + e] + r * bhh[2 * E + e]);
      }
    }
  } else {
    int rb = row - B * S;  // 0..7 -> 16 SCT rows each
    for (int m = rb * 16; m < rb * 16 + 16; ++m) {
      float* r = SCT + (size_t)m * K3;
      for (int n = tid; n < 1512; n += 256) r[n] = (n < 1000) ? gb[n] : 0.f;
    }
  }
}

// ---------- GHC split-K gemm with FUSED h1 (per-step), 32-row tiles: grid (24,8,2) ----------
// A = h1(GI[wl[m]]) computed inline; GHC[m,n] += A . Whh[n, kslice];
// GHC pre-initialized with bhh by k_sm; x==0 blocks side-write H1C for k_pairc.
__global__ __launch_bounds__(256) void k_ghcs(const int* __restrict__ wlb,
                                              const int* __restrict__ wlL,
                                              const float* __restrict__ GI,
                                              const float* __restrict__ bhh,
                                              const float* __restrict__ Whh,
                                              float* __restrict__ GHC,
                                              float* __restrict__ H1C) {
  __shared__ float As[16][32];
  __shared__ float Ws[16][64];
  int tid = threadIdx.x;
  int nBase = blockIdx.x * 64;
  int mBase = blockIdx.y * 32;
  int kbeg = blockIdx.z * 256;
  int tx = tid & 15, ty = tid >> 4;
  int ar = tid & 31, ak = (tid >> 5) * 2;
  int li = tid & 63, lk = (tid >> 6) * 4;
  int w = mBase + ar;
  const float* gi = GI + (size_t)(wlb[w] * 16 + wlL[w]) * K3;
  const float* Wrow = Whh + (size_t)(nBase + li) * E + kbeg;
  int writeH = (blockIdx.x == 0);
  float* hrow = H1C + (size_t)w * E;
  float acc[2][4] = {{0.f,0.f,0.f,0.f},{0.f,0.f,0.f,0.f}};
  int e0 = kbeg + ak;
  float2 g0 = *(const float2*)(gi + e0);
  float2 g1 = *(const float2*)(gi + E + e0);
  float2 g2 = *(const float2*)(gi + 2 * E + e0);
  float2 b0 = *(const float2*)(bhh + e0);
  float2 b1 = *(const float2*)(bhh + E + e0);
  float2 b2 = *(const float2*)(bhh + 2 * E + e0);
  float4 wv = *(const float4*)(Wrow + lk);
  for (int k0 = 0; k0 < 256; k0 += 16) {
    float r0 = sigm(g0.x + b0.x), z0 = sigm(g1.x + b1.x);
    float h0 = (1.f - z0) * tanhf(g2.x + r0 * b2.x);
    float r1 = sigm(g0.y + b0.y), z1 = sigm(g1.y + b1.y);
    float h1v = (1.f - z1) * tanhf(g2.y + r1 * b2.y);
    As[ak + 0][ar] = h0; As[ak + 1][ar] = h1v;
    Ws[lk + 0][li] = wv.x; Ws[lk + 1][li] = wv.y;
    Ws[lk + 2][li] = wv.z; Ws[lk + 3][li] = wv.w;
    if (writeH) *(float2*)(hrow + kbeg + k0 + ak) = make_float2(h0, h1v);
    __syncthreads();
    if (k0 + 16 < 256) {
      int e2 = kbeg + k0 + 16 + ak;
      g0 = *(const float2*)(gi + e2);
      g1 = *(const float2*)(gi + E + e2);
      g2 = *(const float2*)(gi + 2 * E + e2);
      b0 = *(const float2*)(bhh + e2);
      b1 = *(const float2*)(bhh + E + e2);
      b2 = *(const float2*)(bhh + 2 * E + e2);
      wv = *(const float4*)(Wrow + k0 + 16 + lk);
    }
    TILE_FMA32
    __syncthreads();
  }
#pragma unroll
  for (int r = 0; r < 2; ++r) {
    int mm = mBase + ty * 2 + r;
#pragma unroll
    for (int c = 0; c < 4; ++c) {
      int nn = nBase + tx * 4 + c;
      atomicAdd(&GHC[(size_t)mm * K3 + nn], acc[r][c]);
    }
  }
}

// ---------- pair + fc score (h1 from H1C) ----------
__global__ __launch_bounds__(256) void k_pairc(const int* __restrict__ wlb,
                                               const int* __restrict__ wlL,
                                               const int* __restrict__ wlR,
                                               const float* __restrict__ GI,
                                               const float* __restrict__ GHC,
                                               const float* __restrict__ H1C,
                                               const float* __restrict__ wfc,
                                               const float* __restrict__ bfc,
                                               float* __restrict__ PAIR,
                                               float* __restrict__ SCR) {
  __shared__ float sb[256];
  int w = blockIdx.x, tid = threadIdx.x;
  int b = wlb[w], ls = wlL[w], rs = wlR[w];
  const float* gr = GI + (size_t)(b * 16 + rs) * K3;
  const float* gh = GHC + (size_t)w * K3;
  const float* h = H1C + (size_t)w * E;
  float* p = PAIR + (size_t)(b * 16 + ls) * E;
  float part = 0.f;
  for (int e = tid; e < E; e += 256) {
    float r = sigm(gr[e] + gh[e]);
    float z = sigm(gr[E + e] + gh[E + e]);
    float n = tanhf(gr[2 * E + e] + r * gh[2 * E + e]);
    float pv = (1.f - z) * n + z * h[e];
    p[e] = pv;
    part += pv * wfc[e];
  }
  float d = brsum(part, sb);
  if (tid == 0) SCR[b * 16 + ls] = sigm(d + bfc[0]);
}

// ---------- fused sel + scores split-K gemm, 32-row tiles: grid (24, 4, 2) ----------
// Block (0, y, 0) additionally writes pos/wl/xdst for its 32 batch rows.
__global__ __launch_bounds__(256) void k_qscsel(const float* __restrict__ PAIR,
                                                const float* __restrict__ SCR,
                                                const int* __restrict__ pin,
                                                int* __restrict__ pout,
                                                int* __restrict__ wlb,
                                                int* __restrict__ wlL,
                                                int* __restrict__ wlR,
                                                int* __restrict__ xdst,
                                                const float* __restrict__ Gbig,
                                                float* __restrict__ SCT,
                                                int P, int finalMode) {
  __shared__ float As[16][32];
  __shared__ float Ws[16][64];
  __shared__ int sxd[32];
  int tid = threadIdx.x;
  int nBase = blockIdx.x * 64;
  int mBase = blockIdx.y * 32;
  int kbeg = blockIdx.z * 256;
  if (tid < 32) {
    int b = mBase + tid;
    if (finalMode) {
      int xr = b * 16 + pin[b * 16];
      sxd[tid] = xr;
      if (blockIdx.x == 0 && blockIdx.z == 0) xdst[b] = xr;
    } else {
      int L = P + 1;
      int lp[16];
      for (int i = 0; i < L; ++i) lp[i] = pin[b * 16 + i];
      float best = -1e30f; int sel = 0;
      for (int i = 0; i < P; ++i) {
        float v = SCR[b * 16 + lp[i]];
        if (v > best) { best = v; sel = i; }
      }
      int r1i = (sel + 2 < L) ? sel + 2 : L - 1;
      int l1 = lp[sel], r1 = lp[r1i];
      int l0 = (sel > 0) ? lp[sel - 1] : l1;
      int r0 = (sel > 0) ? lp[sel] : r1;
      sxd[tid] = b * 16 + l1;
      if (blockIdx.x == 0 && blockIdx.z == 0) {
        wlb[2 * b] = b;     wlL[2 * b] = l0;     wlR[2 * b] = r0;
        wlb[2 * b + 1] = b; wlL[2 * b + 1] = l1; wlR[2 * b + 1] = r1;
        xdst[b] = b * 16 + l1;
        for (int i = 0; i < L - 1; ++i)
          pout[b * 16 + i] = (i <= sel) ? lp[i] : lp[i + 1];
      }
    }
  }
  __syncthreads();
  int tx = tid & 15, ty = tid >> 4;
  int ar = tid & 31, ak = (tid >> 5) * 2;
  int li = tid & 63, lk = (tid >> 6) * 4;
  float acc[2][4] = {{0.f,0.f,0.f,0.f},{0.f,0.f,0.f,0.f}};
  const float* Arow = PAIR + (size_t)sxd[ar] * E + kbeg;
  int n = nBase + li;
  const float* Wrow = (n < 1512) ? (Gbig + (size_t)n * E + kbeg) : nullptr;
  float2 av = *(const float2*)(Arow + ak);
  float4 wv = Wrow ? *(const float4*)(Wrow + lk) : make_float4(0.f, 0.f, 0.f, 0.f);
  for (int k0 = 0; k0 < 256; k0 += 16) {
    As[ak + 0][ar] = av.x; As[ak + 1][ar] = av.y;
    Ws[lk + 0][li] = wv.x; Ws[lk + 1][li] = wv.y;
    Ws[lk + 2][li] = wv.z; Ws[lk + 3][li] = wv.w;
    __syncthreads();
    if (k0 + 16 < 256) {
      av = *(const float2*)(Arow + k0 + 16 + ak);
      wv = Wrow ? *(const float4*)(Wrow + k0 + 16 + lk) : make_float4(0.f, 0.f, 0.f, 0.f);
    }
    TILE_FMA32
    __syncthreads();
  }
#pragma unroll
  for (int r = 0; r < 2; ++r) {
    int mm = mBase + ty * 2 + r;
#pragma unroll
    for (int c = 0; c < 4; ++c) {
      int nn = nBase + tx * 4 + c;
      if (nn < 1512) atomicAdd(&SCT[(size_t)mm * K3 + nn], acc[r][c]);
    }
  }
}

// ---------- softmax/entropy + A2 build + GI row init + SCT re-init + GHC bhh pre-init ----------
// losses and (final) scores go straight to out
__global__ __launch_bounds__(256) void k_sm(float* __restrict__ SCT,
                                            const float* __restrict__ PAIR,
                                            const int* __restrict__ xdst,
                                            const float* __restrict__ v12,
                                            const float* __restrict__ c0s,
                                            float* __restrict__ outp,
                                            float* __restrict__ A2,
                                            float* __restrict__ GI,
                                            const float* __restrict__ bih,
                                            const float* __restrict__ gb,
                                            float* __restrict__ GHC,
                                            const float* __restrict__ bhh,
                                            int t, int finalMode) {
  __shared__ float sb[256];
  __shared__ float sb2[256];
  __shared__ float sps[E];
  int b = blockIdx.x, tid = threadIdx.x;
  float* row = SCT + (size_t)b * K3;
  int xr = xdst[b];
  const float* sp = PAIR + (size_t)xr * E;
  for (int i = tid; i < E; i += 256) sps[i] = sp[i];
  __syncthreads();
  // bilinear self-score: raw Mqk part in cols 1000..1511
  float part = 0.f;
  for (int i = tid; i < E; i += 256) part += sps[i] * (row[1000 + i] + v12[i]);
  float last = (brsum(part, sb) + c0s[0]) * SCALE;
  float s[4];
  float ml = last;
#pragma unroll
  for (int q = 0; q < 4; ++q) {
    int j = tid + q * 256;
    s[q] = (j < 1000) ? row[j] * SCALE : -1e30f;  // row holds raw dot+gb
    ml = fmaxf(ml, s[q]);
  }
  float mx = brmax(ml, sb);
  float zp = 0.f, s1p = 0.f;
#pragma unroll
  for (int q = 0; q < 4; ++q) {
    int j = tid + q * 256;
    if (j < 1000) { float e = expf(s[q] - mx); zp += e; s1p += e * s[q]; }
  }
  if (tid == 0) { float e = expf(last - mx); zp += e; s1p += e * last; }
  float z, s1;
  brsum2(zp, s1p, sb, sb2, &z, &s1);
  if (tid == 0) outp[NS + b * 16 + t] = mx + logf(z) - s1 / z;
  if (!finalMode) {
    float inv = 1.f / z;
    float* a = A2 + (size_t)b * K3;
#pragma unroll
    for (int q = 0; q < 4; ++q) {
      int j = tid + q * 256;
      if (j < 1000) a[j] = expf(s[q] - mx) * inv;
    }
    if (tid < 24) a[1000 + tid] = 0.f;
    float pr = expf(last - mx) * inv;
    for (int i = tid; i < E; i += 256) a[1024 + i] = pr * sps[i];
    float* g = GI + (size_t)xr * K3;
    for (int n2 = tid; n2 < K3; n2 += 256) g[n2] = bih[n2];
    // re-init SCT row for the next step's split-K accumulation
    for (int n2 = tid; n2 < 1512; n2 += 256) row[n2] = (n2 < 1000) ? gb[n2] : 0.f;
    // GHC bhh pre-init for this batch's two worklist entries (consumed by k_ghcs)
    float* g0 = GHC + (size_t)(2 * b) * K3;
    float* g1 = GHC + (size_t)(2 * b + 1) * K3;
    for (int n2 = tid; n2 < K3; n2 += 256) {
      float bb = bhh[n2];
      g0[n2] = bb; g1[n2] = bb;
    }
  } else {
    float* so = outp + (size_t)b * (R + 1);
#pragma unroll
    for (int q = 0; q < 4; ++q) {
      int j = tid + q * 256;
      if (j < 1000) so[j] = s[q];
    }
    if (tid == 0) so[R] = last;
  }
}

// ---------- fused merged+GI gemm, split-K atomic, 32-row tiles: grid (24,4,4) ----------
__global__ __launch_bounds__(256) void k_giup(const float* __restrict__ A2,
                                              const float* __restrict__ Wbig,
                                              float* __restrict__ GI,
                                              const int* __restrict__ xdst) {
  __shared__ float As[16][32];
  __shared__ float Ws[16][64];
  int tid = threadIdx.x;
  int nBase = blockIdx.x * 64;
  int mBase = blockIdx.y * 32;
  int kbeg = blockIdx.z * 384;
  int tx = tid & 15, ty = tid >> 4;
  int ar = tid & 31, ak = (tid >> 5) * 2;
  int li = tid & 63, wr = tid >> 6;
  float acc[2][4] = {{0.f,0.f,0.f,0.f},{0.f,0.f,0.f,0.f}};
  const float* Arow = A2 + (size_t)(mBase + ar) * K3;
  for (int k0 = kbeg; k0 < kbeg + 384; k0 += 16) {
    float2 av = *(const float2*)(Arow + k0 + ak);
    As[ak + 0][ar] = av.x; As[ak + 1][ar] = av.y;
#pragma unroll
    for (int j = 0; j < 4; ++j)
      Ws[wr * 4 + j][li] = Wbig[(size_t)(k0 + wr * 4 + j) * K3 + nBase + li];
    __syncthreads();
    TILE_FMA32
    __syncthreads();
  }
#pragma unroll
  for (int r = 0; r < 2; ++r) {
    int mm = mBase + ty * 2 + r;
    size_t crow = (size_t)xdst[mm] * K3;
#pragma unroll
    for (int c = 0; c < 4; ++c) {
      int nn = nBase + tx * 4 + c;
      atomicAdd(&GI[crow + nn], acc[r][c]);
    }
  }
}

extern "C" void kernel_launch(void* const* d_in, const int* in_sizes, int n_in,
                              void* d_out, int out_size, void* d_ws, size_t ws_size,
                              hipStream_t stream) {
  (void)in_sizes; (void)n_in; (void)out_size; (void)ws_size;
  const int* tokens = (const int*)d_in[0];
  const float* emb = (const float*)d_in[1];
  const float* W_ih = (const float*)d_in[2];
  const float* W_hh = (const float*)d_in[3];
  const float* b_ih = (const float*)d_in[4];
  const float* b_hh = (const float*)d_in[5];
  const float* w_fc = (const float*)d_in[6];
  const float* b_fc = (const float*)d_in[7];
  const float* Wq = (const float*)d_in[8];
  const float* bq = (const float*)d_in[9];
  const float* Wk = (const float*)d_in[10];
  const float* bk = (const float*)d_in[11];
  float* out = (float*)d_out;

  float* ws = (float*)d_ws;
  size_t o = 0;
  float* GI = ws + o;    o += (size_t)B * S * K3;
  float* GHC = ws + o;   o += (size_t)NW0 * K3;
  float* H1C = ws + o;   o += (size_t)NW0 * E;
  float* PAIR = ws + o;  o += (size_t)B * S * E;
  float* Wbig = ws + o;  o += (size_t)K3 * K3;       // [EW(1000) | 0(24) | W_ih^T(512)] k-major
  float* Gbig = ws + o;  o += (size_t)1512 * E;      // [G2(1000) ; Mqk(512)]
  float* KREL = ws + o;  o += (size_t)R * E;
  float* WqT = ws + o;   o += (size_t)E * E;
  float* WkT = ws + o;   o += (size_t)E * E;
  float* SCT = ws + o;   o += (size_t)B * K3;
  float* A2 = ws + o;    o += (size_t)B * K3;
  float* gb = ws + o;    o += 1024;
  float* v12 = ws + o;   o += 512;
  float* c0s = ws + o;   o += 16;
  float* SCR = ws + o;   o += B * 16;
  int* pos0 = (int*)(ws + o); o += B * 16;
  int* pos1 = (int*)(ws + o); o += B * 16;
  int* wlb = (int*)(ws + o);  o += NW0;
  int* wlL = (int*)(ws + o);  o += NW0;
  int* wlR = (int*)(ws + o);  o += NW0;
  int* xdst = (int*)(ws + o); o += B;

  // ---- setup: 6 launches ----
  k_prep<<<336, 256, 0, stream>>>(Wq, Wk, W_ih, WqT, WkT, Wbig, pos0, wlb, wlL, wlR, out);
  // KREL = emb@Wk^T + bk  AND  Wbig[0:1000] = EW = emb@W_ih^T  (one dual-output 32-row gemm)
  k_gemmD32<<<dim3(32, 32), 256, 0, stream>>>(emb, E, R, Wk, E, bk, KREL, E,
                                              W_ih, K3, Wbig, K3, E);
  // G2 = KREL@Wq ; Mqk = Wq^T@Wk ; v12/c0s/gb
  k_setup3<<<199, 256, 0, stream>>>(KREL, WqT, WkT, bq, bk, Gbig, v12, c0s, gb);
  // GI gather + fused setup-h1 + SCT pre-init
  k_giinit<<<B * S + 8, 256, 0, stream>>>(tokens, Wbig, b_ih, GI, gb, SCT, b_hh, H1C);
  k_gemm32<<<dim3(24, 60), 256, 0, stream>>>(H1C, E, NW0, W_hh, K3, E, b_hh, GHC, K3);
  k_pairc<<<NW0, 256, 0, stream>>>(wlb, wlL, wlR, GI, GHC, H1C, w_fc, b_fc, PAIR, SCR);

  // ---- 14 merge steps, 5 kernels each (h1 fused into ghcs) ----
  for (int t = 0; t < 14; ++t) {
    int* pin = (t & 1) ? pos1 : pos0;
    int* pout = (t & 1) ? pos0 : pos1;
    k_qscsel<<<dim3(24, 4, 2), 256, 0, stream>>>(PAIR, SCR, pin, pout, wlb, wlL, wlR,
                                                 xdst, Gbig, SCT, 15 - t, 0);
    k_sm<<<B, 256, 0, stream>>>(SCT, PAIR, xdst, v12, c0s, out, A2, GI, b_ih, gb,
                                GHC, b_hh, t, 0);
    k_giup<<<dim3(24, 4, 4), 256, 0, stream>>>(A2, Wbig, GI, xdst);
    k_ghcs<<<dim3(24, 8, 2), 256, 0, stream>>>(wlb, wlL, GI, b_hh, W_hh, GHC, H1C);
    k_pairc<<<NWS, 256, 0, stream>>>(wlb, wlL, wlR, GI, GHC, H1C, w_fc, b_fc, PAIR, SCR);
  }

  // ---- final: h2 = PAIR[b][pos0[b*16]]; attention, scores+loss straight to out ----
  k_qscsel<<<dim3(24, 4, 2), 256, 0, stream>>>(PAIR, SCR, pos0, pos1, wlb, wlL, wlR,
                                               xdst, Gbig, SCT, 1, 1);
  k_sm<<<B, 256, 0, stream>>>(SCT, PAIR, xdst, v12, c0s, out, A2, GI, b_ih, gb,
                              GHC, b_hh, 15, 1);
}

// Round 12
// 1450.192 us; speedup vs baseline: 1.1036x; 1.1036x over previous
//
#include <hip/hip_runtime.h>

#define B 128
#define S 16
#define E 512
#define R 1000
#define K3 1536
#define NW0 1920   // init worklist: 128 b * 15 pairs
#define NWS 256    // per-step worklist: 128 b * 2 entries
#define NS (B * (R + 1))
#define SCALE 0.04419417382415922f

static __device__ __forceinline__ float sigm(float x) { return 1.f / (1.f + expf(-x)); }

// ---------- block reductions (256 threads) ----------
static __device__ __forceinline__ float brsum(float v, float* sb) {
  int tid = threadIdx.x;
  sb[tid] = v; __syncthreads();
  for (int s = 128; s > 0; s >>= 1) {
    if (tid < s) sb[tid] += sb[tid + s];
    __syncthreads();
  }
  float r = sb[0]; __syncthreads();
  return r;
}
static __device__ __forceinline__ float brmax(float v, float* sb) {
  int tid = threadIdx.x;
  sb[tid] = v; __syncthreads();
  for (int s = 128; s > 0; s >>= 1) {
    if (tid < s) sb[tid] = fmaxf(sb[tid], sb[tid + s]);
    __syncthreads();
  }
  float r = sb[0]; __syncthreads();
  return r;
}
// paired sum reduction: (v1,v2) -> (sb[0], sb2[0])
static __device__ __forceinline__ void brsum2(float v1, float v2, float* sb, float* sb2,
                                              float* o1, float* o2) {
  int tid = threadIdx.x;
  sb[tid] = v1; sb2[tid] = v2; __syncthreads();
  for (int s = 128; s > 0; s >>= 1) {
    if (tid < s) { sb[tid] += sb[tid + s]; sb2[tid] += sb2[tid + s]; }
    __syncthreads();
  }
  *o1 = sb[0]; *o2 = sb2[0]; __syncthreads();
}

#define TILE_FMA \
  _Pragma("unroll") \
  for (int k = 0; k < 16; ++k) { \
    float4 a4 = *(const float4*)&As[k][ty * 4]; \
    float4 w4 = *(const float4*)&Ws[k][tx * 4]; \
    acc[0][0] = fmaf(a4.x, w4.x, acc[0][0]); acc[0][1] = fmaf(a4.x, w4.y, acc[0][1]); \
    acc[0][2] = fmaf(a4.x, w4.z, acc[0][2]); acc[0][3] = fmaf(a4.x, w4.w, acc[0][3]); \
    acc[1][0] = fmaf(a4.y, w4.x, acc[1][0]); acc[1][1] = fmaf(a4.y, w4.y, acc[1][1]); \
    acc[1][2] = fmaf(a4.y, w4.z, acc[1][2]); acc[1][3] = fmaf(a4.y, w4.w, acc[1][3]); \
    acc[2][0] = fmaf(a4.z, w4.x, acc[2][0]); acc[2][1] = fmaf(a4.z, w4.y, acc[2][1]); \
    acc[2][2] = fmaf(a4.z, w4.z, acc[2][2]); acc[2][3] = fmaf(a4.z, w4.w, acc[2][3]); \
    acc[3][0] = fmaf(a4.w, w4.x, acc[3][0]); acc[3][1] = fmaf(a4.w, w4.y, acc[3][1]); \
    acc[3][2] = fmaf(a4.w, w4.z, acc[3][2]); acc[3][3] = fmaf(a4.w, w4.w, acc[3][3]); \
  }

// 32-row-tile inner product: acc[2][4], A in As[16][32], W in Ws[16][64]
#define TILE_FMA32 \
  _Pragma("unroll") \
  for (int k = 0; k < 16; ++k) { \
    float2 a2 = *(const float2*)&As[k][ty * 2]; \
    float4 w4 = *(const float4*)&Ws[k][tx * 4]; \
    acc[0][0] = fmaf(a2.x, w4.x, acc[0][0]); acc[0][1] = fmaf(a2.x, w4.y, acc[0][1]); \
    acc[0][2] = fmaf(a2.x, w4.z, acc[0][2]); acc[0][3] = fmaf(a2.x, w4.w, acc[0][3]); \
    acc[1][0] = fmaf(a2.y, w4.x, acc[1][0]); acc[1][1] = fmaf(a2.y, w4.y, acc[1][1]); \
    acc[1][2] = fmaf(a2.y, w4.z, acc[1][2]); acc[1][3] = fmaf(a2.y, w4.w, acc[1][3]); \
  }

// ---------- generic tiled gemm (standalone body — VGPR~44 codegen) ----------
__global__ __launch_bounds__(256) void k_gemm(const float* __restrict__ A, int lda, int M,
                                              const float* __restrict__ W, int N, int K,
                                              const float* __restrict__ bias, float scale,
                                              float* __restrict__ C, int ldc) {
  __shared__ float As[16][64];
  __shared__ float Ws[16][64];
  int tid = threadIdx.x;
  int mBase = blockIdx.y * 64;
  int nBase = blockIdx.x * 64;
  int tx = tid & 15, ty = tid >> 4;
  int li = tid & 63;
  int lk = (tid >> 6) * 4;
  float acc[4][4] = {{0.f,0.f,0.f,0.f},{0.f,0.f,0.f,0.f},{0.f,0.f,0.f,0.f},{0.f,0.f,0.f,0.f}};
  int m = mBase + li;
  const float* Arow = (m < M) ? (A + (size_t)m * lda) : nullptr;
  int n = nBase + li;
  const float* Wrow = (n < N) ? (W + (size_t)n * K) : nullptr;

  float4 av = Arow ? *(const float4*)(Arow + lk) : make_float4(0.f, 0.f, 0.f, 0.f);
  float4 wv = Wrow ? *(const float4*)(Wrow + lk) : make_float4(0.f, 0.f, 0.f, 0.f);

  for (int k0 = 0; k0 < K; k0 += 16) {
    As[lk + 0][li] = av.x; As[lk + 1][li] = av.y;
    As[lk + 2][li] = av.z; As[lk + 3][li] = av.w;
    Ws[lk + 0][li] = wv.x; Ws[lk + 1][li] = wv.y;
    Ws[lk + 2][li] = wv.z; Ws[lk + 3][li] = wv.w;
    __syncthreads();
    if (k0 + 16 < K) {
      av = Arow ? *(const float4*)(Arow + k0 + 16 + lk) : make_float4(0.f, 0.f, 0.f, 0.f);
      wv = Wrow ? *(const float4*)(Wrow + k0 + 16 + lk) : make_float4(0.f, 0.f, 0.f, 0.f);
    }
    TILE_FMA
    __syncthreads();
  }
#pragma unroll
  for (int r = 0; r < 4; ++r) {
    int mm = mBase + ty * 4 + r;
    if (mm >= M) continue;
#pragma unroll
    for (int c = 0; c < 4; ++c) {
      int nn = nBase + tx * 4 + c;
      if (nn >= N) continue;
      float v = acc[r][c] * scale;
      if (bias) v += bias[nn];
      C[(size_t)mm * ldc + nn] = v;
    }
  }
}

// ---------- dual-output gemm: n<N1 -> W1,b1,C1 ; else W2,C2 (no bias) ----------
__global__ __launch_bounds__(256) void k_gemmD(const float* __restrict__ A, int lda, int M,
                                               const float* __restrict__ W1, int N1,
                                               const float* __restrict__ b1,
                                               float* __restrict__ C1, int ldc1,
                                               const float* __restrict__ W2, int N2,
                                               float* __restrict__ C2, int ldc2, int K) {
  __shared__ float As[16][64];
  __shared__ float Ws[16][64];
  int tid = threadIdx.x;
  int mBase = blockIdx.y * 64;
  int nBase = blockIdx.x * 64;
  int tx = tid & 15, ty = tid >> 4;
  int li = tid & 63;
  int lk = (tid >> 6) * 4;
  float acc[4][4] = {{0.f,0.f,0.f,0.f},{0.f,0.f,0.f,0.f},{0.f,0.f,0.f,0.f},{0.f,0.f,0.f,0.f}};
  int m = mBase + li;
  const float* Arow = (m < M) ? (A + (size_t)m * lda) : nullptr;
  int n = nBase + li;
  const float* Wrow = nullptr;
  if (n < N1) Wrow = W1 + (size_t)n * K;
  else if (n < N1 + N2) Wrow = W2 + (size_t)(n - N1) * K;

  float4 av = Arow ? *(const float4*)(Arow + lk) : make_float4(0.f, 0.f, 0.f, 0.f);
  float4 wv = Wrow ? *(const float4*)(Wrow + lk) : make_float4(0.f, 0.f, 0.f, 0.f);

  for (int k0 = 0; k0 < K; k0 += 16) {
    As[lk + 0][li] = av.x; As[lk + 1][li] = av.y;
    As[lk + 2][li] = av.z; As[lk + 3][li] = av.w;
    Ws[lk + 0][li] = wv.x; Ws[lk + 1][li] = wv.y;
    Ws[lk + 2][li] = wv.z; Ws[lk + 3][li] = wv.w;
    __syncthreads();
    if (k0 + 16 < K) {
      av = Arow ? *(const float4*)(Arow + k0 + 16 + lk) : make_float4(0.f, 0.f, 0.f, 0.f);
      wv = Wrow ? *(const float4*)(Wrow + k0 + 16 + lk) : make_float4(0.f, 0.f, 0.f, 0.f);
    }
    TILE_FMA
    __syncthreads();
  }
#pragma unroll
  for (int r = 0; r < 4; ++r) {
    int mm = mBase + ty * 4 + r;
    if (mm >= M) continue;
#pragma unroll
    for (int c = 0; c < 4; ++c) {
      int nn = nBase + tx * 4 + c;
      if (nn < N1) {
        float v = acc[r][c];
        if (b1) v += b1[nn];
        C1[(size_t)mm * ldc1 + nn] = v;
      } else if (nn < N1 + N2) {
        C2[(size_t)mm * ldc2 + (nn - N1)] = acc[r][c];
      }
    }
  }
}

// ---------- 64x64 gemm core for setup3 only ----------
static __device__ void dev_g64(float (*As)[64], float (*Ws)[64], int tid,
                               int mBase, int nBase,
                               const float* __restrict__ A, int lda, int M,
                               const float* __restrict__ W, int N, int K,
                               const float* __restrict__ bias, float scale,
                               float* __restrict__ C, int ldc) {
  int tx = tid & 15, ty = tid >> 4;
  int li = tid & 63;
  int lk = (tid >> 6) * 4;
  float acc[4][4] = {{0.f,0.f,0.f,0.f},{0.f,0.f,0.f,0.f},{0.f,0.f,0.f,0.f},{0.f,0.f,0.f,0.f}};
  int m = mBase + li;
  const float* Arow = (m < M) ? (A + (size_t)m * lda) : nullptr;
  int n = nBase + li;
  const float* Wrow = (n < N) ? (W + (size_t)n * K) : nullptr;

  float4 av = Arow ? *(const float4*)(Arow + lk) : make_float4(0.f, 0.f, 0.f, 0.f);
  float4 wv = Wrow ? *(const float4*)(Wrow + lk) : make_float4(0.f, 0.f, 0.f, 0.f);

  for (int k0 = 0; k0 < K; k0 += 16) {
    As[lk + 0][li] = av.x; As[lk + 1][li] = av.y;
    As[lk + 2][li] = av.z; As[lk + 3][li] = av.w;
    Ws[lk + 0][li] = wv.x; Ws[lk + 1][li] = wv.y;
    Ws[lk + 2][li] = wv.z; Ws[lk + 3][li] = wv.w;
    __syncthreads();
    if (k0 + 16 < K) {
      av = Arow ? *(const float4*)(Arow + k0 + 16 + lk) : make_float4(0.f, 0.f, 0.f, 0.f);
      wv = Wrow ? *(const float4*)(Wrow + k0 + 16 + lk) : make_float4(0.f, 0.f, 0.f, 0.f);
    }
    TILE_FMA
    __syncthreads();
  }
#pragma unroll
  for (int r = 0; r < 4; ++r) {
    int mm = mBase + ty * 4 + r;
    if (mm >= M) continue;
#pragma unroll
    for (int c = 0; c < 4; ++c) {
      int nn = nBase + tx * 4 + c;
      if (nn >= N) continue;
      float v = acc[r][c] * scale;
      if (bias) v += bias[nn];
      C[(size_t)mm * ldc + nn] = v;
    }
  }
}

// ---------- 64x64 transpose tile (device) ----------
static __device__ void dev_tr64(float (*t)[65], int tid, const float* __restrict__ src,
                                int Cc, float* __restrict__ dst, int ldd, int bx, int by) {
  int tx = tid & 15, ty = tid >> 4;
  int rb = by * 64, cb = bx * 64;
#pragma unroll
  for (int i = 0; i < 4; ++i) {
    int r = rb + ty + i * 16;
    float4 v = *(const float4*)(src + (size_t)r * Cc + cb + tx * 4);
    t[ty + i * 16][tx * 4 + 0] = v.x; t[ty + i * 16][tx * 4 + 1] = v.y;
    t[ty + i * 16][tx * 4 + 2] = v.z; t[ty + i * 16][tx * 4 + 3] = v.w;
  }
  __syncthreads();
#pragma unroll
  for (int i = 0; i < 4; ++i) {
    int c = cb + ty + i * 16;
    float4 v;
    v.x = t[tx * 4 + 0][ty + i * 16]; v.y = t[tx * 4 + 1][ty + i * 16];
    v.z = t[tx * 4 + 2][ty + i * 16]; v.w = t[tx * 4 + 3][ty + i * 16];
    *(float4*)(dst + (size_t)c * ldd + rb + tx * 4) = v;
  }
}

// ---------- setup L1: transposes + initwl + Wbig pad + out col14 zero ----------
__global__ __launch_bounds__(256) void k_prep(const float* __restrict__ Wq,
                                              const float* __restrict__ Wk,
                                              const float* __restrict__ Wih,
                                              float* __restrict__ WqT,
                                              float* __restrict__ WkT,
                                              float* __restrict__ Wbig,
                                              int* __restrict__ pos,
                                              int* __restrict__ wlb,
                                              int* __restrict__ wlL,
                                              int* __restrict__ wlR,
                                              float* __restrict__ outp) {
  __shared__ float t[64][65];
  int blk = blockIdx.x, tid = threadIdx.x;
  if (blk < 64) {
    dev_tr64(t, tid, Wq, E, WqT, E, blk & 7, blk >> 3);
  } else if (blk < 128) {
    int j = blk - 64;
    dev_tr64(t, tid, Wk, E, WkT, E, j & 7, j >> 3);
  } else if (blk < 320) {
    int j = blk - 128;
    dev_tr64(t, tid, Wih, E, Wbig + (size_t)1024 * K3, K3, j & 7, j >> 3);
  } else if (blk < 328) {
    int idx = (blk - 320) * 256 + tid;
    if (idx < B * 16) pos[idx] = idx & 15;
    if (idx < NW0) {
      wlb[idx] = idx / 15;
      int i = idx % 15;
      wlL[idx] = i;
      wlR[idx] = i + 1;
    }
    if (idx < B) outp[NS + idx * 16 + 14] = 0.f;  // loss col 14 is identically 0
  } else {
    int idx = (blk - 328) * 256 + tid;
    for (int i = idx; i < 24 * K3; i += 8 * 256) Wbig[(size_t)1000 * K3 + i] = 0.f;
  }
}

// ---------- setup L3: G2 gemm [0,128), Mqk gemm [128,192), misc [192,199) ----------
__global__ __launch_bounds__(256) void k_setup3(const float* __restrict__ KREL,
                                                const float* __restrict__ WqT,
                                                const float* __restrict__ WkT,
                                                const float* __restrict__ bq,
                                                const float* __restrict__ bk,
                                                float* __restrict__ Gbig,
                                                float* __restrict__ v12,
                                                float* __restrict__ c0s,
                                                float* __restrict__ gb) {
  __shared__ float As[16][64];
  __shared__ float Ws[16][64];
  int blk = blockIdx.x, tid = threadIdx.x;
  if (blk < 128) {
    dev_g64(As, Ws, tid, (blk >> 3) * 64, (blk & 7) * 64, KREL, E, R, WqT, E, E,
            nullptr, 1.f, Gbig, E);
  } else if (blk < 192) {
    int j = blk - 128;
    dev_g64(As, Ws, tid, (j >> 3) * 64, (j & 7) * 64, WqT, E, E, WkT, E, E,
            nullptr, 1.f, Gbig + (size_t)1000 * E, E);
  } else {
    int m = blk - 192;
    if (m < 2) {
      int i = m * 256 + tid;
      const float* wq = WqT + (size_t)i * E;
      const float* wk = WkT + (size_t)i * E;
      float s = 0.f;
      for (int e = 0; e < E; ++e) s += wq[e] * bk[e] + bq[e] * wk[e];
      v12[i] = s;
    } else if (m == 2) {
      float* sb = (float*)As;
      float p = 0.f;
      for (int e = tid; e < E; e += 256) p += bq[e] * bk[e];
      float s = brsum(p, sb);
      if (tid == 0) c0s[0] = s;
    } else {
      int r = (m - 3) * 256 + tid;
      if (r < R) {
        const float* kr = KREL + (size_t)r * E;
        float s = 0.f;
        for (int e = 0; e < E; ++e) s += bq[e] * kr[e];
        gb[r] = s;
      }
    }
  }
}

// ---------- GI init gather (+ fused h1 for setup worklist) + SCT pre-init ----------
__global__ __launch_bounds__(256) void k_giinit(const int* __restrict__ tokens,
                                                const float* __restrict__ Wbig,
                                                const float* __restrict__ bih,
                                                float* __restrict__ GI,
                                                const float* __restrict__ gb,
                                                float* __restrict__ SCT,
                                                const float* __restrict__ bhh,
                                                float* __restrict__ H1C) {
  int row = blockIdx.x, tid = threadIdx.x;
  if (row < B * S) {
    int tok = tokens[row];
    const float4* src = (const float4*)(Wbig + (size_t)tok * K3);
    const float4* bv = (const float4*)bih;
    float* girow = GI + (size_t)row * K3;
    float4* dst = (float4*)girow;
    for (int i = tid; i < K3 / 4; i += 256) {
      float4 a = src[i], b = bv[i];
      dst[i] = make_float4(a.x + b.x, a.y + b.y, a.z + b.z, a.w + b.w);
    }
    int i16 = row & 15;
    if (i16 < 15) {  // fused h1 for worklist entry w = (row>>4)*15 + i16
      __syncthreads();  // GI row visible (this block's own writes)
      float* h = H1C + (size_t)((row >> 4) * 15 + i16) * E;
      for (int e = tid; e < E; e += 256) {
        float r = sigm(girow[e] + bhh[e]);
        float z = sigm(girow[E + e] + bhh[E + e]);
        h[e] = (1.f - z) * tanhf(girow[2 * E + e] + r * bhh[2 * E + e]);
      }
    }
  } else {
    int rb = row - B * S;  // 0..7 -> 16 SCT rows each
    for (int m = rb * 16; m < rb * 16 + 16; ++m) {
      float* r = SCT + (size_t)m * K3;
      for (int n = tid; n < 1512; n += 256) r[n] = (n < 1000) ? gb[n] : 0.f;
    }
  }
}

// ---------- h1 for worklist entries (per-step; + GHC pre-init with bhh) ----------
__global__ __launch_bounds__(256) void k_h1c(const int* __restrict__ wlb,
                                             const int* __restrict__ wlL,
                                             const float* __restrict__ GI,
                                             const float* __restrict__ bhh,
                                             float* __restrict__ H1C,
                                             float* __restrict__ GHC) {
  int w = blockIdx.x, tid = threadIdx.x;
  const float* gi = GI + (size_t)(wlb[w] * 16 + wlL[w]) * K3;
  float* h = H1C + (size_t)w * E;
  for (int e = tid; e < E; e += 256) {
    float r = sigm(gi[e] + bhh[e]);
    float z = sigm(gi[E + e] + bhh[E + e]);
    h[e] = (1.f - z) * tanhf(gi[2 * E + e] + r * bhh[2 * E + e]);
  }
  if (GHC) {
    float* g = GHC + (size_t)w * K3;
    for (int n = tid; n < K3; n += 256) g[n] = bhh[n];
  }
}

// ---------- GHC split-K gemm, 32-row tiles: grid (24, 8, 2) ----------
// GHC[m,n] += H1C[m, kslice] . Whh[n, kslice]; GHC pre-initialized with bhh
__global__ __launch_bounds__(256) void k_ghcs(const float* __restrict__ H1C,
                                              const float* __restrict__ Whh,
                                              float* __restrict__ GHC) {
  __shared__ float As[16][32];
  __shared__ float Ws[16][64];
  int tid = threadIdx.x;
  int nBase = blockIdx.x * 64;
  int mBase = blockIdx.y * 32;
  int kbeg = blockIdx.z * 256;
  int tx = tid & 15, ty = tid >> 4;
  int ar = tid & 31, ak = (tid >> 5) * 2;
  int li = tid & 63, lk = (tid >> 6) * 4;
  float acc[2][4] = {{0.f,0.f,0.f,0.f},{0.f,0.f,0.f,0.f}};
  const float* Arow = H1C + (size_t)(mBase + ar) * E + kbeg;
  const float* Wrow = Whh + (size_t)(nBase + li) * E + kbeg;
  float2 av = *(const float2*)(Arow + ak);
  float4 wv = *(const float4*)(Wrow + lk);
  for (int k0 = 0; k0 < 256; k0 += 16) {
    As[ak + 0][ar] = av.x; As[ak + 1][ar] = av.y;
    Ws[lk + 0][li] = wv.x; Ws[lk + 1][li] = wv.y;
    Ws[lk + 2][li] = wv.z; Ws[lk + 3][li] = wv.w;
    __syncthreads();
    if (k0 + 16 < 256) {
      av = *(const float2*)(Arow + k0 + 16 + ak);
      wv = *(const float4*)(Wrow + k0 + 16 + lk);
    }
    TILE_FMA32
    __syncthreads();
  }
#pragma unroll
  for (int r = 0; r < 2; ++r) {
    int mm = mBase + ty * 2 + r;
#pragma unroll
    for (int c = 0; c < 4; ++c) {
      int nn = nBase + tx * 4 + c;
      atomicAdd(&GHC[(size_t)mm * K3 + nn], acc[r][c]);
    }
  }
}

// ---------- pair + fc score (h1 from H1C) ----------
__global__ __launch_bounds__(256) void k_pairc(const int* __restrict__ wlb,
                                               const int* __restrict__ wlL,
                                               const int* __restrict__ wlR,
                                               const float* __restrict__ GI,
                                               const float* __restrict__ GHC,
                                               const float* __restrict__ H1C,
                                               const float* __restrict__ wfc,
                                               const float* __restrict__ bfc,
                                               float* __restrict__ PAIR,
                                               float* __restrict__ SCR) {
  __shared__ float sb[256];
  int w = blockIdx.x, tid = threadIdx.x;
  int b = wlb[w], ls = wlL[w], rs = wlR[w];
  const float* gr = GI + (size_t)(b * 16 + rs) * K3;
  const float* gh = GHC + (size_t)w * K3;
  const float* h = H1C + (size_t)w * E;
  float* p = PAIR + (size_t)(b * 16 + ls) * E;
  float part = 0.f;
  for (int e = tid; e < E; e += 256) {
    float r = sigm(gr[e] + gh[e]);
    float z = sigm(gr[E + e] + gh[E + e]);
    float n = tanhf(gr[2 * E + e] + r * gh[2 * E + e]);
    float pv = (1.f - z) * n + z * h[e];
    p[e] = pv;
    part += pv * wfc[e];
  }
  float d = brsum(part, sb);
  if (tid == 0) SCR[b * 16 + ls] = sigm(d + bfc[0]);
}

// ---------- fused sel + scores split-K gemm, 32-row tiles: grid (24, 4, 2) ----------
// Block (0, y, 0) writes pos/wl/xdst; blocks (x<16, y, 1) write GI[xdst]=bih (2 rows each).
__global__ __launch_bounds__(256) void k_qscsel(const float* __restrict__ PAIR,
                                                const float* __restrict__ SCR,
                                                const int* __restrict__ pin,
                                                int* __restrict__ pout,
                                                int* __restrict__ wlb,
                                                int* __restrict__ wlL,
                                                int* __restrict__ wlR,
                                                int* __restrict__ xdst,
                                                const float* __restrict__ Gbig,
                                                float* __restrict__ SCT,
                                                float* __restrict__ GI,
                                                const float* __restrict__ bih,
                                                int P, int finalMode) {
  __shared__ float As[16][32];
  __shared__ float Ws[16][64];
  __shared__ int sxd[32];
  int tid = threadIdx.x;
  int nBase = blockIdx.x * 64;
  int mBase = blockIdx.y * 32;
  int kbeg = blockIdx.z * 256;
  if (tid < 32) {
    int b = mBase + tid;
    if (finalMode) {
      int xr = b * 16 + pin[b * 16];
      sxd[tid] = xr;
      if (blockIdx.x == 0 && blockIdx.z == 0) xdst[b] = xr;
    } else {
      int L = P + 1;
      int lp[16];
      for (int i = 0; i < L; ++i) lp[i] = pin[b * 16 + i];
      float best = -1e30f; int sel = 0;
      for (int i = 0; i < P; ++i) {
        float v = SCR[b * 16 + lp[i]];
        if (v > best) { best = v; sel = i; }
      }
      int r1i = (sel + 2 < L) ? sel + 2 : L - 1;
      int l1 = lp[sel], r1 = lp[r1i];
      int l0 = (sel > 0) ? lp[sel - 1] : l1;
      int r0 = (sel > 0) ? lp[sel] : r1;
      sxd[tid] = b * 16 + l1;
      if (blockIdx.x == 0 && blockIdx.z == 0) {
        wlb[2 * b] = b;     wlL[2 * b] = l0;     wlR[2 * b] = r0;
        wlb[2 * b + 1] = b; wlL[2 * b + 1] = l1; wlR[2 * b + 1] = r1;
        xdst[b] = b * 16 + l1;
        for (int i = 0; i < L - 1; ++i)
          pout[b * 16 + i] = (i <= sel) ? lp[i] : lp[i + 1];
      }
    }
  }
  __syncthreads();
  // GI[merged row] = bih, moved off k_sm's critical path. Deterministic duplicate-safe
  // values; old merged-row GI has no readers after this point (sm reads PAIR/SCT only).
  if (!finalMode && blockIdx.z == 1 && blockIdx.x < 16) {
#pragma unroll
    for (int r = 0; r < 2; ++r) {
      float* g = GI + (size_t)sxd[blockIdx.x * 2 + r] * K3;
      for (int i = tid; i < K3; i += 256) g[i] = bih[i];
    }
  }
  int tx = tid & 15, ty = tid >> 4;
  int ar = tid & 31, ak = (tid >> 5) * 2;
  int li = tid & 63, lk = (tid >> 6) * 4;
  float acc[2][4] = {{0.f,0.f,0.f,0.f},{0.f,0.f,0.f,0.f}};
  const float* Arow = PAIR + (size_t)sxd[ar] * E + kbeg;
  int n = nBase + li;
  const float* Wrow = (n < 1512) ? (Gbig + (size_t)n * E + kbeg) : nullptr;
  float2 av = *(const float2*)(Arow + ak);
  float4 wv = Wrow ? *(const float4*)(Wrow + lk) : make_float4(0.f, 0.f, 0.f, 0.f);
  for (int k0 = 0; k0 < 256; k0 += 16) {
    As[ak + 0][ar] = av.x; As[ak + 1][ar] = av.y;
    Ws[lk + 0][li] = wv.x; Ws[lk + 1][li] = wv.y;
    Ws[lk + 2][li] = wv.z; Ws[lk + 3][li] = wv.w;
    __syncthreads();
    if (k0 + 16 < 256) {
      av = *(const float2*)(Arow + k0 + 16 + ak);
      wv = Wrow ? *(const float4*)(Wrow + k0 + 16 + lk) : make_float4(0.f, 0.f, 0.f, 0.f);
    }
    TILE_FMA32
    __syncthreads();
  }
#pragma unroll
  for (int r = 0; r < 2; ++r) {
    int mm = mBase + ty * 2 + r;
#pragma unroll
    for (int c = 0; c < 4; ++c) {
      int nn = nBase + tx * 4 + c;
      if (nn < 1512) atomicAdd(&SCT[(size_t)mm * K3 + nn], acc[r][c]);
    }
  }
}

// ---------- softmax/entropy + A2 build + SCT re-init ----------
// losses and (final) scores go straight to out
__global__ __launch_bounds__(256) void k_sm(float* __restrict__ SCT,
                                            const float* __restrict__ PAIR,
                                            const int* __restrict__ xdst,
                                            const float* __restrict__ v12,
                                            const float* __restrict__ c0s,
                                            float* __restrict__ outp,
                                            float* __restrict__ A2,
                                            const float* __restrict__ gb,
                                            int t, int finalMode) {
  __shared__ float sb[256];
  __shared__ float sb2[256];
  __shared__ float sps[E];
  int b = blockIdx.x, tid = threadIdx.x;
  float* row = SCT + (size_t)b * K3;
  int xr = xdst[b];
  const float* sp = PAIR + (size_t)xr * E;
  for (int i = tid; i < E; i += 256) sps[i] = sp[i];
  __syncthreads();
  // bilinear self-score: raw Mqk part in cols 1000..1511
  float part = 0.f;
  for (int i = tid; i < E; i += 256) part += sps[i] * (row[1000 + i] + v12[i]);
  float last = (brsum(part, sb) + c0s[0]) * SCALE;
  float s[4];
  float ml = last;
#pragma unroll
  for (int q = 0; q < 4; ++q) {
    int j = tid + q * 256;
    s[q] = (j < 1000) ? row[j] * SCALE : -1e30f;  // row holds raw dot+gb
    ml = fmaxf(ml, s[q]);
  }
  float mx = brmax(ml, sb);
  float zp = 0.f, s1p = 0.f;
#pragma unroll
  for (int q = 0; q < 4; ++q) {
    int j = tid + q * 256;
    if (j < 1000) { float e = expf(s[q] - mx); zp += e; s1p += e * s[q]; }
  }
  if (tid == 0) { float e = expf(last - mx); zp += e; s1p += e * last; }
  float z, s1;
  brsum2(zp, s1p, sb, sb2, &z, &s1);
  if (tid == 0) outp[NS + b * 16 + t] = mx + logf(z) - s1 / z;
  if (!finalMode) {
    float inv = 1.f / z;
    float* a = A2 + (size_t)b * K3;
#pragma unroll
    for (int q = 0; q < 4; ++q) {
      int j = tid + q * 256;
      if (j < 1000) a[j] = expf(s[q] - mx) * inv;
    }
    if (tid < 24) a[1000 + tid] = 0.f;
    float pr = expf(last - mx) * inv;
    for (int i = tid; i < E; i += 256) a[1024 + i] = pr * sps[i];
    // re-init SCT row for the next step's split-K accumulation
    for (int n2 = tid; n2 < 1512; n2 += 256) row[n2] = (n2 < 1000) ? gb[n2] : 0.f;
  } else {
    float* so = outp + (size_t)b * (R + 1);
#pragma unroll
    for (int q = 0; q < 4; ++q) {
      int j = tid + q * 256;
      if (j < 1000) so[j] = s[q];
    }
    if (tid == 0) so[R] = last;
  }
}

// ---------- fused merged+GI gemm, split-K atomic, 32-row tiles: grid (24,4,4) ----------
__global__ __launch_bounds__(256) void k_giup(const float* __restrict__ A2,
                                              const float* __restrict__ Wbig,
                                              float* __restrict__ GI,
                                              const int* __restrict__ xdst) {
  __shared__ float As[16][32];
  __shared__ float Ws[16][64];
  int tid = threadIdx.x;
  int nBase = blockIdx.x * 64;
  int mBase = blockIdx.y * 32;
  int kbeg = blockIdx.z * 384;
  int tx = tid & 15, ty = tid >> 4;
  int ar = tid & 31, ak = (tid >> 5) * 2;
  int li = tid & 63, wr = tid >> 6;
  float acc[2][4] = {{0.f,0.f,0.f,0.f},{0.f,0.f,0.f,0.f}};
  const float* Arow = A2 + (size_t)(mBase + ar) * K3;
  for (int k0 = kbeg; k0 < kbeg + 384; k0 += 16) {
    float2 av = *(const float2*)(Arow + k0 + ak);
    As[ak + 0][ar] = av.x; As[ak + 1][ar] = av.y;
#pragma unroll
    for (int j = 0; j < 4; ++j)
      Ws[wr * 4 + j][li] = Wbig[(size_t)(k0 + wr * 4 + j) * K3 + nBase + li];
    __syncthreads();
    TILE_FMA32
    __syncthreads();
  }
#pragma unroll
  for (int r = 0; r < 2; ++r) {
    int mm = mBase + ty * 2 + r;
    size_t crow = (size_t)xdst[mm] * K3;
#pragma unroll
    for (int c = 0; c < 4; ++c) {
      int nn = nBase + tx * 4 + c;
      atomicAdd(&GI[crow + nn], acc[r][c]);
    }
  }
}

extern "C" void kernel_launch(void* const* d_in, const int* in_sizes, int n_in,
                              void* d_out, int out_size, void* d_ws, size_t ws_size,
                              hipStream_t stream) {
  (void)in_sizes; (void)n_in; (void)out_size; (void)ws_size;
  const int* tokens = (const int*)d_in[0];
  const float* emb = (const float*)d_in[1];
  const float* W_ih = (const float*)d_in[2];
  const float* W_hh = (const float*)d_in[3];
  const float* b_ih = (const float*)d_in[4];
  const float* b_hh = (const float*)d_in[5];
  const float* w_fc = (const float*)d_in[6];
  const float* b_fc = (const float*)d_in[7];
  const float* Wq = (const float*)d_in[8];
  const float* bq = (const float*)d_in[9];
  const float* Wk = (const float*)d_in[10];
  const float* bk = (const float*)d_in[11];
  float* out = (float*)d_out;

  float* ws = (float*)d_ws;
  size_t o = 0;
  float* GI = ws + o;    o += (size_t)B * S * K3;
  float* GHC = ws + o;   o += (size_t)NW0 * K3;
  float* H1C = ws + o;   o += (size_t)NW0 * E;
  float* PAIR = ws + o;  o += (size_t)B * S * E;
  float* Wbig = ws + o;  o += (size_t)K3 * K3;       // [EW(1000) | 0(24) | W_ih^T(512)] k-major
  float* Gbig = ws + o;  o += (size_t)1512 * E;      // [G2(1000) ; Mqk(512)]
  float* KREL = ws + o;  o += (size_t)R * E;
  float* WqT = ws + o;   o += (size_t)E * E;
  float* WkT = ws + o;   o += (size_t)E * E;
  float* SCT = ws + o;   o += (size_t)B * K3;
  float* A2 = ws + o;    o += (size_t)B * K3;
  float* gb = ws + o;    o += 1024;
  float* v12 = ws + o;   o += 512;
  float* c0s = ws + o;   o += 16;
  float* SCR = ws + o;   o += B * 16;
  int* pos0 = (int*)(ws + o); o += B * 16;
  int* pos1 = (int*)(ws + o); o += B * 16;
  int* wlb = (int*)(ws + o);  o += NW0;
  int* wlL = (int*)(ws + o);  o += NW0;
  int* wlR = (int*)(ws + o);  o += NW0;
  int* xdst = (int*)(ws + o); o += B;

  // ---- setup: 6 launches (64-row gemms — measured optimum) ----
  k_prep<<<336, 256, 0, stream>>>(Wq, Wk, W_ih, WqT, WkT, Wbig, pos0, wlb, wlL, wlR, out);
  // KREL = emb@Wk^T + bk  AND  Wbig[0:1000] = EW = emb@W_ih^T  (one dual-output gemm)
  k_gemmD<<<dim3(32, 16), 256, 0, stream>>>(emb, E, R, Wk, E, bk, KREL, E,
                                            W_ih, K3, Wbig, K3, E);
  // G2 = KREL@Wq ; Mqk = Wq^T@Wk ; v12/c0s/gb
  k_setup3<<<199, 256, 0, stream>>>(KREL, WqT, WkT, bq, bk, Gbig, v12, c0s, gb);
  // GI gather + fused setup-h1 + SCT pre-init
  k_giinit<<<B * S + 8, 256, 0, stream>>>(tokens, Wbig, b_ih, GI, gb, SCT, b_hh, H1C);
  k_gemm<<<dim3(24, 30), 256, 0, stream>>>(H1C, E, NW0, W_hh, K3, E, b_hh, 1.f, GHC, K3);
  k_pairc<<<NW0, 256, 0, stream>>>(wlb, wlL, wlR, GI, GHC, H1C, w_fc, b_fc, PAIR, SCR);

  // ---- 14 merge steps, 6 kernels each (round-10 structure) ----
  for (int t = 0; t < 14; ++t) {
    int* pin = (t & 1) ? pos1 : pos0;
    int* pout = (t & 1) ? pos0 : pos1;
    k_qscsel<<<dim3(24, 4, 2), 256, 0, stream>>>(PAIR, SCR, pin, pout, wlb, wlL, wlR,
                                                 xdst, Gbig, SCT, GI, b_ih, 15 - t, 0);
    k_sm<<<B, 256, 0, stream>>>(SCT, PAIR, xdst, v12, c0s, out, A2, gb, t, 0);
    k_giup<<<dim3(24, 4, 4), 256, 0, stream>>>(A2, Wbig, GI, xdst);
    k_h1c<<<NWS, 256, 0, stream>>>(wlb, wlL, GI, b_hh, H1C, GHC);
    k_ghcs<<<dim3(24, 8, 2), 256, 0, stream>>>(H1C, W_hh, GHC);
    k_pairc<<<NWS, 256, 0, stream>>>(wlb, wlL, wlR, GI, GHC, H1C, w_fc, b_fc, PAIR, SCR);
  }

  // ---- final: h2 = PAIR[b][pos0[b*16]]; attention, scores+loss straight to out ----
  k_qscsel<<<dim3(24, 4, 2), 256, 0, stream>>>(PAIR, SCR, pos0, pos1, wlb, wlL, wlR,
                                               xdst, Gbig, SCT, GI, b_ih, 1, 1);
  k_sm<<<B, 256, 0, stream>>>(SCT, PAIR, xdst, v12, c0s, out, A2, gb, 15, 1);
}

// Round 13
// 1358.132 us; speedup vs baseline: 1.1784x; 1.0678x over previous
//
#include <hip/hip_runtime.h>

#define B 128
#define S 16
#define E 512
#define R 1000
#define K3 1536
#define NW0 1920   // init worklist: 128 b * 15 pairs
#define NWS 256    // per-step worklist: 128 b * 2 entries
#define NS (B * (R + 1))
#define SCALE 0.04419417382415922f

static __device__ __forceinline__ float sigm(float x) { return 1.f / (1.f + expf(-x)); }

// ---------- block reductions (256 threads) ----------
static __device__ __forceinline__ float brsum(float v, float* sb) {
  int tid = threadIdx.x;
  sb[tid] = v; __syncthreads();
  for (int s = 128; s > 0; s >>= 1) {
    if (tid < s) sb[tid] += sb[tid + s];
    __syncthreads();
  }
  float r = sb[0]; __syncthreads();
  return r;
}
static __device__ __forceinline__ float brmax(float v, float* sb) {
  int tid = threadIdx.x;
  sb[tid] = v; __syncthreads();
  for (int s = 128; s > 0; s >>= 1) {
    if (tid < s) sb[tid] = fmaxf(sb[tid], sb[tid + s]);
    __syncthreads();
  }
  float r = sb[0]; __syncthreads();
  return r;
}
// paired sum reduction: (v1,v2) -> (sb[0], sb2[0])
static __device__ __forceinline__ void brsum2(float v1, float v2, float* sb, float* sb2,
                                              float* o1, float* o2) {
  int tid = threadIdx.x;
  sb[tid] = v1; sb2[tid] = v2; __syncthreads();
  for (int s = 128; s > 0; s >>= 1) {
    if (tid < s) { sb[tid] += sb[tid + s]; sb2[tid] += sb2[tid + s]; }
    __syncthreads();
  }
  *o1 = sb[0]; *o2 = sb2[0]; __syncthreads();
}

#define TILE_FMA \
  _Pragma("unroll") \
  for (int k = 0; k < 16; ++k) { \
    float4 a4 = *(const float4*)&As[k][ty * 4]; \
    float4 w4 = *(const float4*)&Ws[k][tx * 4]; \
    acc[0][0] = fmaf(a4.x, w4.x, acc[0][0]); acc[0][1] = fmaf(a4.x, w4.y, acc[0][1]); \
    acc[0][2] = fmaf(a4.x, w4.z, acc[0][2]); acc[0][3] = fmaf(a4.x, w4.w, acc[0][3]); \
    acc[1][0] = fmaf(a4.y, w4.x, acc[1][0]); acc[1][1] = fmaf(a4.y, w4.y, acc[1][1]); \
    acc[1][2] = fmaf(a4.y, w4.z, acc[1][2]); acc[1][3] = fmaf(a4.y, w4.w, acc[1][3]); \
    acc[2][0] = fmaf(a4.z, w4.x, acc[2][0]); acc[2][1] = fmaf(a4.z, w4.y, acc[2][1]); \
    acc[2][2] = fmaf(a4.z, w4.z, acc[2][2]); acc[2][3] = fmaf(a4.z, w4.w, acc[2][3]); \
    acc[3][0] = fmaf(a4.w, w4.x, acc[3][0]); acc[3][1] = fmaf(a4.w, w4.y, acc[3][1]); \
    acc[3][2] = fmaf(a4.w, w4.z, acc[3][2]); acc[3][3] = fmaf(a4.w, w4.w, acc[3][3]); \
  }

// 32-row-tile inner product: acc[2][4], A in As[16][32], W in Ws[16][64]
#define TILE_FMA32 \
  _Pragma("unroll") \
  for (int k = 0; k < 16; ++k) { \
    float2 a2 = *(const float2*)&As[k][ty * 2]; \
    float4 w4 = *(const float4*)&Ws[k][tx * 4]; \
    acc[0][0] = fmaf(a2.x, w4.x, acc[0][0]); acc[0][1] = fmaf(a2.x, w4.y, acc[0][1]); \
    acc[0][2] = fmaf(a2.x, w4.z, acc[0][2]); acc[0][3] = fmaf(a2.x, w4.w, acc[0][3]); \
    acc[1][0] = fmaf(a2.y, w4.x, acc[1][0]); acc[1][1] = fmaf(a2.y, w4.y, acc[1][1]); \
    acc[1][2] = fmaf(a2.y, w4.z, acc[1][2]); acc[1][3] = fmaf(a2.y, w4.w, acc[1][3]); \
  }

// ---------- generic tiled gemm (standalone body — VGPR~44 codegen) ----------
__global__ __launch_bounds__(256) void k_gemm(const float* __restrict__ A, int lda, int M,
                                              const float* __restrict__ W, int N, int K,
                                              const float* __restrict__ bias, float scale,
                                              float* __restrict__ C, int ldc) {
  __shared__ float As[16][64];
  __shared__ float Ws[16][64];
  int tid = threadIdx.x;
  int mBase = blockIdx.y * 64;
  int nBase = blockIdx.x * 64;
  int tx = tid & 15, ty = tid >> 4;
  int li = tid & 63;
  int lk = (tid >> 6) * 4;
  float acc[4][4] = {{0.f,0.f,0.f,0.f},{0.f,0.f,0.f,0.f},{0.f,0.f,0.f,0.f},{0.f,0.f,0.f,0.f}};
  int m = mBase + li;
  const float* Arow = (m < M) ? (A + (size_t)m * lda) : nullptr;
  int n = nBase + li;
  const float* Wrow = (n < N) ? (W + (size_t)n * K) : nullptr;

  float4 av = Arow ? *(const float4*)(Arow + lk) : make_float4(0.f, 0.f, 0.f, 0.f);
  float4 wv = Wrow ? *(const float4*)(Wrow + lk) : make_float4(0.f, 0.f, 0.f, 0.f);

  for (int k0 = 0; k0 < K; k0 += 16) {
    As[lk + 0][li] = av.x; As[lk + 1][li] = av.y;
    As[lk + 2][li] = av.z; As[lk + 3][li] = av.w;
    Ws[lk + 0][li] = wv.x; Ws[lk + 1][li] = wv.y;
    Ws[lk + 2][li] = wv.z; Ws[lk + 3][li] = wv.w;
    __syncthreads();
    if (k0 + 16 < K) {
      av = Arow ? *(const float4*)(Arow + k0 + 16 + lk) : make_float4(0.f, 0.f, 0.f, 0.f);
      wv = Wrow ? *(const float4*)(Wrow + k0 + 16 + lk) : make_float4(0.f, 0.f, 0.f, 0.f);
    }
    TILE_FMA
    __syncthreads();
  }
#pragma unroll
  for (int r = 0; r < 4; ++r) {
    int mm = mBase + ty * 4 + r;
    if (mm >= M) continue;
#pragma unroll
    for (int c = 0; c < 4; ++c) {
      int nn = nBase + tx * 4 + c;
      if (nn >= N) continue;
      float v = acc[r][c] * scale;
      if (bias) v += bias[nn];
      C[(size_t)mm * ldc + nn] = v;
    }
  }
}

// ---------- dual-output gemm: n<N1 -> W1,b1,C1 ; else W2,C2 (no bias) ----------
__global__ __launch_bounds__(256) void k_gemmD(const float* __restrict__ A, int lda, int M,
                                               const float* __restrict__ W1, int N1,
                                               const float* __restrict__ b1,
                                               float* __restrict__ C1, int ldc1,
                                               const float* __restrict__ W2, int N2,
                                               float* __restrict__ C2, int ldc2, int K) {
  __shared__ float As[16][64];
  __shared__ float Ws[16][64];
  int tid = threadIdx.x;
  int mBase = blockIdx.y * 64;
  int nBase = blockIdx.x * 64;
  int tx = tid & 15, ty = tid >> 4;
  int li = tid & 63;
  int lk = (tid >> 6) * 4;
  float acc[4][4] = {{0.f,0.f,0.f,0.f},{0.f,0.f,0.f,0.f},{0.f,0.f,0.f,0.f},{0.f,0.f,0.f,0.f}};
  int m = mBase + li;
  const float* Arow = (m < M) ? (A + (size_t)m * lda) : nullptr;
  int n = nBase + li;
  const float* Wrow = nullptr;
  if (n < N1) Wrow = W1 + (size_t)n * K;
  else if (n < N1 + N2) Wrow = W2 + (size_t)(n - N1) * K;

  float4 av = Arow ? *(const float4*)(Arow + lk) : make_float4(0.f, 0.f, 0.f, 0.f);
  float4 wv = Wrow ? *(const float4*)(Wrow + lk) : make_float4(0.f, 0.f, 0.f, 0.f);

  for (int k0 = 0; k0 < K; k0 += 16) {
    As[lk + 0][li] = av.x; As[lk + 1][li] = av.y;
    As[lk + 2][li] = av.z; As[lk + 3][li] = av.w;
    Ws[lk + 0][li] = wv.x; Ws[lk + 1][li] = wv.y;
    Ws[lk + 2][li] = wv.z; Ws[lk + 3][li] = wv.w;
    __syncthreads();
    if (k0 + 16 < K) {
      av = Arow ? *(const float4*)(Arow + k0 + 16 + lk) : make_float4(0.f, 0.f, 0.f, 0.f);
      wv = Wrow ? *(const float4*)(Wrow + k0 + 16 + lk) : make_float4(0.f, 0.f, 0.f, 0.f);
    }
    TILE_FMA
    __syncthreads();
  }
#pragma unroll
  for (int r = 0; r < 4; ++r) {
    int mm = mBase + ty * 4 + r;
    if (mm >= M) continue;
#pragma unroll
    for (int c = 0; c < 4; ++c) {
      int nn = nBase + tx * 4 + c;
      if (nn < N1) {
        float v = acc[r][c];
        if (b1) v += b1[nn];
        C1[(size_t)mm * ldc1 + nn] = v;
      } else if (nn < N1 + N2) {
        C2[(size_t)mm * ldc2 + (nn - N1)] = acc[r][c];
      }
    }
  }
}

// ---------- 64x64 gemm core for setup3 only ----------
static __device__ void dev_g64(float (*As)[64], float (*Ws)[64], int tid,
                               int mBase, int nBase,
                               const float* __restrict__ A, int lda, int M,
                               const float* __restrict__ W, int N, int K,
                               const float* __restrict__ bias, float scale,
                               float* __restrict__ C, int ldc) {
  int tx = tid & 15, ty = tid >> 4;
  int li = tid & 63;
  int lk = (tid >> 6) * 4;
  float acc[4][4] = {{0.f,0.f,0.f,0.f},{0.f,0.f,0.f,0.f},{0.f,0.f,0.f,0.f},{0.f,0.f,0.f,0.f}};
  int m = mBase + li;
  const float* Arow = (m < M) ? (A + (size_t)m * lda) : nullptr;
  int n = nBase + li;
  const float* Wrow = (n < N) ? (W + (size_t)n * K) : nullptr;

  float4 av = Arow ? *(const float4*)(Arow + lk) : make_float4(0.f, 0.f, 0.f, 0.f);
  float4 wv = Wrow ? *(const float4*)(Wrow + lk) : make_float4(0.f, 0.f, 0.f, 0.f);

  for (int k0 = 0; k0 < K; k0 += 16) {
    As[lk + 0][li] = av.x; As[lk + 1][li] = av.y;
    As[lk + 2][li] = av.z; As[lk + 3][li] = av.w;
    Ws[lk + 0][li] = wv.x; Ws[lk + 1][li] = wv.y;
    Ws[lk + 2][li] = wv.z; Ws[lk + 3][li] = wv.w;
    __syncthreads();
    if (k0 + 16 < K) {
      av = Arow ? *(const float4*)(Arow + k0 + 16 + lk) : make_float4(0.f, 0.f, 0.f, 0.f);
      wv = Wrow ? *(const float4*)(Wrow + k0 + 16 + lk) : make_float4(0.f, 0.f, 0.f, 0.f);
    }
    TILE_FMA
    __syncthreads();
  }
#pragma unroll
  for (int r = 0; r < 4; ++r) {
    int mm = mBase + ty * 4 + r;
    if (mm >= M) continue;
#pragma unroll
    for (int c = 0; c < 4; ++c) {
      int nn = nBase + tx * 4 + c;
      if (nn >= N) continue;
      float v = acc[r][c] * scale;
      if (bias) v += bias[nn];
      C[(size_t)mm * ldc + nn] = v;
    }
  }
}

// ---------- 64x64 transpose tile (device) ----------
static __device__ void dev_tr64(float (*t)[65], int tid, const float* __restrict__ src,
                                int Cc, float* __restrict__ dst, int ldd, int bx, int by) {
  int tx = tid & 15, ty = tid >> 4;
  int rb = by * 64, cb = bx * 64;
#pragma unroll
  for (int i = 0; i < 4; ++i) {
    int r = rb + ty + i * 16;
    float4 v = *(const float4*)(src + (size_t)r * Cc + cb + tx * 4);
    t[ty + i * 16][tx * 4 + 0] = v.x; t[ty + i * 16][tx * 4 + 1] = v.y;
    t[ty + i * 16][tx * 4 + 2] = v.z; t[ty + i * 16][tx * 4 + 3] = v.w;
  }
  __syncthreads();
#pragma unroll
  for (int i = 0; i < 4; ++i) {
    int c = cb + ty + i * 16;
    float4 v;
    v.x = t[tx * 4 + 0][ty + i * 16]; v.y = t[tx * 4 + 1][ty + i * 16];
    v.z = t[tx * 4 + 2][ty + i * 16]; v.w = t[tx * 4 + 3][ty + i * 16];
    *(float4*)(dst + (size_t)c * ldd + rb + tx * 4) = v;
  }
}

// ---------- setup L1: transposes + initwl + Wbig pad + out col14 zero ----------
__global__ __launch_bounds__(256) void k_prep(const float* __restrict__ Wq,
                                              const float* __restrict__ Wk,
                                              const float* __restrict__ Wih,
                                              float* __restrict__ WqT,
                                              float* __restrict__ WkT,
                                              float* __restrict__ Wbig,
                                              int* __restrict__ pos,
                                              int* __restrict__ wlb,
                                              int* __restrict__ wlL,
                                              int* __restrict__ wlR,
                                              float* __restrict__ outp) {
  __shared__ float t[64][65];
  int blk = blockIdx.x, tid = threadIdx.x;
  if (blk < 64) {
    dev_tr64(t, tid, Wq, E, WqT, E, blk & 7, blk >> 3);
  } else if (blk < 128) {
    int j = blk - 64;
    dev_tr64(t, tid, Wk, E, WkT, E, j & 7, j >> 3);
  } else if (blk < 320) {
    int j = blk - 128;
    dev_tr64(t, tid, Wih, E, Wbig + (size_t)1024 * K3, K3, j & 7, j >> 3);
  } else if (blk < 328) {
    int idx = (blk - 320) * 256 + tid;
    if (idx < B * 16) pos[idx] = idx & 15;
    if (idx < NW0) {
      wlb[idx] = idx / 15;
      int i = idx % 15;
      wlL[idx] = i;
      wlR[idx] = i + 1;
    }
    if (idx < B) outp[NS + idx * 16 + 14] = 0.f;  // loss col 14 is identically 0
  } else {
    int idx = (blk - 328) * 256 + tid;
    for (int i = idx; i < 24 * K3; i += 8 * 256) Wbig[(size_t)1000 * K3 + i] = 0.f;
  }
}

// ---------- setup L3: G2 [0,128) | Mqk [128,192) | misc [192,199)
//            | GI gather + h1 all positions [199,199+2048) | SCT zero [2247,2255) ----------
__global__ __launch_bounds__(256) void k_setup3(const float* __restrict__ KREL,
                                                const float* __restrict__ WqT,
                                                const float* __restrict__ WkT,
                                                const float* __restrict__ bq,
                                                const float* __restrict__ bk,
                                                float* __restrict__ Gbig,
                                                float* __restrict__ v12,
                                                float* __restrict__ c0s,
                                                float* __restrict__ gb,
                                                const int* __restrict__ tokens,
                                                const float* __restrict__ Wbig,
                                                const float* __restrict__ bih,
                                                const float* __restrict__ bhh,
                                                float* __restrict__ GI,
                                                float* __restrict__ H1P,
                                                float* __restrict__ SCT) {
  __shared__ float As[16][64];
  __shared__ float Ws[16][64];
  int blk = blockIdx.x, tid = threadIdx.x;
  if (blk < 128) {
    dev_g64(As, Ws, tid, (blk >> 3) * 64, (blk & 7) * 64, KREL, E, R, WqT, E, E,
            nullptr, 1.f, Gbig, E);
  } else if (blk < 192) {
    int j = blk - 128;
    dev_g64(As, Ws, tid, (j >> 3) * 64, (j & 7) * 64, WqT, E, E, WkT, E, E,
            nullptr, 1.f, Gbig + (size_t)1000 * E, E);
  } else if (blk < 199) {
    int m = blk - 192;
    if (m < 2) {
      int i = m * 256 + tid;
      const float* wq = WqT + (size_t)i * E;
      const float* wk = WkT + (size_t)i * E;
      float s = 0.f;
      for (int e = 0; e < E; ++e) s += wq[e] * bk[e] + bq[e] * wk[e];
      v12[i] = s;
    } else if (m == 2) {
      float* sb = (float*)As;
      float p = 0.f;
      for (int e = tid; e < E; e += 256) p += bq[e] * bk[e];
      float s = brsum(p, sb);
      if (tid == 0) c0s[0] = s;
    } else {
      int r = (m - 3) * 256 + tid;
      if (r < R) {
        const float* kr = KREL + (size_t)r * E;
        float s = 0.f;
        for (int e = 0; e < E; ++e) s += bq[e] * kr[e];
        gb[r] = s;
      }
    }
  } else if (blk < 199 + B * S) {
    int row = blk - 199;
    int tok = tokens[row];
    const float4* src = (const float4*)(Wbig + (size_t)tok * K3);
    const float4* bv = (const float4*)bih;
    float* girow = GI + (size_t)row * K3;
    float4* dst = (float4*)girow;
    for (int i = tid; i < K3 / 4; i += 256) {
      float4 a = src[i], b = bv[i];
      dst[i] = make_float4(a.x + b.x, a.y + b.y, a.z + b.z, a.w + b.w);
    }
    __syncthreads();  // GI row visible (this block's own writes)
    float* h = H1P + (size_t)row * E;
    for (int e = tid; e < E; e += 256) {
      float r = sigm(girow[e] + bhh[e]);
      float z = sigm(girow[E + e] + bhh[E + e]);
      h[e] = (1.f - z) * tanhf(girow[2 * E + e] + r * bhh[2 * E + e]);
    }
  } else {
    int rb = blk - (199 + B * S);  // 0..7 -> 16 SCT rows each
    for (int m = rb * 16; m < rb * 16 + 16; ++m) {
      float* r = SCT + (size_t)m * K3;
      for (int n = tid; n < 1512; n += 256) r[n] = 0.f;
    }
  }
}

// ---------- per-step h1: one block per batch; recompute position xdst[b] ----------
// also pre-inits GHCP[xdst] row with bhh for the split-K accumulation
__global__ __launch_bounds__(256) void k_h1c(const int* __restrict__ xdst,
                                             const float* __restrict__ GI,
                                             const float* __restrict__ bhh,
                                             float* __restrict__ H1P,
                                             float* __restrict__ GHCP) {
  int p = xdst[blockIdx.x], tid = threadIdx.x;
  const float* gi = GI + (size_t)p * K3;
  float* h = H1P + (size_t)p * E;
  for (int e = tid; e < E; e += 256) {
    float r = sigm(gi[e] + bhh[e]);
    float z = sigm(gi[E + e] + bhh[E + e]);
    h[e] = (1.f - z) * tanhf(gi[2 * E + e] + r * bhh[2 * E + e]);
  }
  float* g = GHCP + (size_t)p * K3;
  for (int n = tid; n < K3; n += 256) g[n] = bhh[n];
}

// ---------- GHC split-K gemm, 32-row tiles, position-indirect: grid (24, 4, 2) ----------
// GHCP[xdst[m], n] += H1P[xdst[m], kslice] . Whh[n, kslice]; pre-initialized with bhh
__global__ __launch_bounds__(256) void k_ghcs(const int* __restrict__ xdst,
                                              const float* __restrict__ H1P,
                                              const float* __restrict__ Whh,
                                              float* __restrict__ GHCP) {
  __shared__ float As[16][32];
  __shared__ float Ws[16][64];
  __shared__ int sp[32];
  int tid = threadIdx.x;
  int nBase = blockIdx.x * 64;
  int mBase = blockIdx.y * 32;
  int kbeg = blockIdx.z * 256;
  if (tid < 32) sp[tid] = xdst[mBase + tid];
  __syncthreads();
  int tx = tid & 15, ty = tid >> 4;
  int ar = tid & 31, ak = (tid >> 5) * 2;
  int li = tid & 63, lk = (tid >> 6) * 4;
  float acc[2][4] = {{0.f,0.f,0.f,0.f},{0.f,0.f,0.f,0.f}};
  const float* Arow = H1P + (size_t)sp[ar] * E + kbeg;
  const float* Wrow = Whh + (size_t)(nBase + li) * E + kbeg;
  float2 av = *(const float2*)(Arow + ak);
  float4 wv = *(const float4*)(Wrow + lk);
  for (int k0 = 0; k0 < 256; k0 += 16) {
    As[ak + 0][ar] = av.x; As[ak + 1][ar] = av.y;
    Ws[lk + 0][li] = wv.x; Ws[lk + 1][li] = wv.y;
    Ws[lk + 2][li] = wv.z; Ws[lk + 3][li] = wv.w;
    __syncthreads();
    if (k0 + 16 < 256) {
      av = *(const float2*)(Arow + k0 + 16 + ak);
      wv = *(const float4*)(Wrow + k0 + 16 + lk);
    }
    TILE_FMA32
    __syncthreads();
  }
#pragma unroll
  for (int r = 0; r < 2; ++r) {
    size_t crow = (size_t)sp[ty * 2 + r] * K3;
#pragma unroll
    for (int c = 0; c < 4; ++c) {
      int nn = nBase + tx * 4 + c;
      atomicAdd(&GHCP[crow + nn], acc[r][c]);
    }
  }
}

// ---------- pair + fc score (position-keyed H1P/GHCP caches) ----------
__global__ __launch_bounds__(256) void k_pairc(const int* __restrict__ wlb,
                                               const int* __restrict__ wlL,
                                               const int* __restrict__ wlR,
                                               const float* __restrict__ GI,
                                               const float* __restrict__ GHCP,
                                               const float* __restrict__ H1P,
                                               const float* __restrict__ wfc,
                                               const float* __restrict__ bfc,
                                               float* __restrict__ PAIR,
                                               float* __restrict__ SCR) {
  __shared__ float sb[256];
  int w = blockIdx.x, tid = threadIdx.x;
  int b = wlb[w], ls = wlL[w], rs = wlR[w];
  int lp = b * 16 + ls;
  const float* gr = GI + (size_t)(b * 16 + rs) * K3;
  const float* gh = GHCP + (size_t)lp * K3;
  const float* h = H1P + (size_t)lp * E;
  float* p = PAIR + (size_t)lp * E;
  float part = 0.f;
  for (int e = tid; e < E; e += 256) {
    float r = sigm(gr[e] + gh[e]);
    float z = sigm(gr[E + e] + gh[E + e]);
    float n = tanhf(gr[2 * E + e] + r * gh[2 * E + e]);
    float pv = (1.f - z) * n + z * h[e];
    p[e] = pv;
    part += pv * wfc[e];
  }
  float d = brsum(part, sb);
  if (tid == 0) SCR[b * 16 + ls] = sigm(d + bfc[0]);
}

// ---------- fused sel + scores split-K gemm, 32-row tiles: grid (24, 4, 2) ----------
// Block (0, y, 0) writes pos/wl/xdst; blocks (x<16, y, 1) write GI[xdst]=bih (2 rows each).
__global__ __launch_bounds__(256) void k_qscsel(const float* __restrict__ PAIR,
                                                const float* __restrict__ SCR,
                                                const int* __restrict__ pin,
                                                int* __restrict__ pout,
                                                int* __restrict__ wlb,
                                                int* __restrict__ wlL,
                                                int* __restrict__ wlR,
                                                int* __restrict__ xdst,
                                                const float* __restrict__ Gbig,
                                                float* __restrict__ SCT,
                                                float* __restrict__ GI,
                                                const float* __restrict__ bih,
                                                int P, int finalMode) {
  __shared__ float As[16][32];
  __shared__ float Ws[16][64];
  __shared__ int sxd[32];
  int tid = threadIdx.x;
  int nBase = blockIdx.x * 64;
  int mBase = blockIdx.y * 32;
  int kbeg = blockIdx.z * 256;
  if (tid < 32) {
    int b = mBase + tid;
    if (finalMode) {
      int xr = b * 16 + pin[b * 16];
      sxd[tid] = xr;
      if (blockIdx.x == 0 && blockIdx.z == 0) xdst[b] = xr;
    } else {
      int L = P + 1;
      int lp[16];
      for (int i = 0; i < L; ++i) lp[i] = pin[b * 16 + i];
      float best = -1e30f; int sel = 0;
      for (int i = 0; i < P; ++i) {
        float v = SCR[b * 16 + lp[i]];
        if (v > best) { best = v; sel = i; }
      }
      int r1i = (sel + 2 < L) ? sel + 2 : L - 1;
      int l1 = lp[sel], r1 = lp[r1i];
      int l0 = (sel > 0) ? lp[sel - 1] : l1;
      int r0 = (sel > 0) ? lp[sel] : r1;
      sxd[tid] = b * 16 + l1;
      if (blockIdx.x == 0 && blockIdx.z == 0) {
        wlb[2 * b] = b;     wlL[2 * b] = l0;     wlR[2 * b] = r0;
        wlb[2 * b + 1] = b; wlL[2 * b + 1] = l1; wlR[2 * b + 1] = r1;
        xdst[b] = b * 16 + l1;
        for (int i = 0; i < L - 1; ++i)
          pout[b * 16 + i] = (i <= sel) ? lp[i] : lp[i + 1];
      }
    }
  }
  __syncthreads();
  // GI[merged row] = bih, off k_sm's critical path (duplicate-safe deterministic writes).
  if (!finalMode && blockIdx.z == 1 && blockIdx.x < 16) {
#pragma unroll
    for (int r = 0; r < 2; ++r) {
      float* g = GI + (size_t)sxd[blockIdx.x * 2 + r] * K3;
      for (int i = tid; i < K3; i += 256) g[i] = bih[i];
    }
  }
  int tx = tid & 15, ty = tid >> 4;
  int ar = tid & 31, ak = (tid >> 5) * 2;
  int li = tid & 63, lk = (tid >> 6) * 4;
  float acc[2][4] = {{0.f,0.f,0.f,0.f},{0.f,0.f,0.f,0.f}};
  const float* Arow = PAIR + (size_t)sxd[ar] * E + kbeg;
  int n = nBase + li;
  const float* Wrow = (n < 1512) ? (Gbig + (size_t)n * E + kbeg) : nullptr;
  float2 av = *(const float2*)(Arow + ak);
  float4 wv = Wrow ? *(const float4*)(Wrow + lk) : make_float4(0.f, 0.f, 0.f, 0.f);
  for (int k0 = 0; k0 < 256; k0 += 16) {
    As[ak + 0][ar] = av.x; As[ak + 1][ar] = av.y;
    Ws[lk + 0][li] = wv.x; Ws[lk + 1][li] = wv.y;
    Ws[lk + 2][li] = wv.z; Ws[lk + 3][li] = wv.w;
    __syncthreads();
    if (k0 + 16 < 256) {
      av = *(const float2*)(Arow + k0 + 16 + ak);
      wv = Wrow ? *(const float4*)(Wrow + k0 + 16 + lk) : make_float4(0.f, 0.f, 0.f, 0.f);
    }
    TILE_FMA32
    __syncthreads();
  }
#pragma unroll
  for (int r = 0; r < 2; ++r) {
    int mm = mBase + ty * 2 + r;
#pragma unroll
    for (int c = 0; c < 4; ++c) {
      int nn = nBase + tx * 4 + c;
      if (nn < 1512) atomicAdd(&SCT[(size_t)mm * K3 + nn], acc[r][c]);
    }
  }
}

// ---------- softmax/entropy + A2 build + SCT re-init (zeros) ----------
// SCT holds RAW dots (zero-init); gb added here. losses/(final) scores straight to out.
__global__ __launch_bounds__(256) void k_sm(float* __restrict__ SCT,
                                            const float* __restrict__ PAIR,
                                            const int* __restrict__ xdst,
                                            const float* __restrict__ v12,
                                            const float* __restrict__ c0s,
                                            float* __restrict__ outp,
                                            float* __restrict__ A2,
                                            const float* __restrict__ gb,
                                            int t, int finalMode) {
  __shared__ float sb[256];
  __shared__ float sb2[256];
  __shared__ float sps[E];
  int b = blockIdx.x, tid = threadIdx.x;
  float* row = SCT + (size_t)b * K3;
  int xr = xdst[b];
  const float* sp = PAIR + (size_t)xr * E;
  for (int i = tid; i < E; i += 256) sps[i] = sp[i];
  __syncthreads();
  // bilinear self-score: raw Mqk part in cols 1000..1511
  float part = 0.f;
  for (int i = tid; i < E; i += 256) part += sps[i] * (row[1000 + i] + v12[i]);
  float last = (brsum(part, sb) + c0s[0]) * SCALE;
  float s[4];
  float ml = last;
#pragma unroll
  for (int q = 0; q < 4; ++q) {
    int j = tid + q * 256;
    s[q] = (j < 1000) ? (row[j] + gb[j]) * SCALE : -1e30f;  // raw dot + gb
    ml = fmaxf(ml, s[q]);
  }
  float mx = brmax(ml, sb);
  float zp = 0.f, s1p = 0.f;
#pragma unroll
  for (int q = 0; q < 4; ++q) {
    int j = tid + q * 256;
    if (j < 1000) { float e = expf(s[q] - mx); zp += e; s1p += e * s[q]; }
  }
  if (tid == 0) { float e = expf(last - mx); zp += e; s1p += e * last; }
  float z, s1;
  brsum2(zp, s1p, sb, sb2, &z, &s1);
  if (tid == 0) outp[NS + b * 16 + t] = mx + logf(z) - s1 / z;
  if (!finalMode) {
    float inv = 1.f / z;
    float* a = A2 + (size_t)b * K3;
#pragma unroll
    for (int q = 0; q < 4; ++q) {
      int j = tid + q * 256;
      if (j < 1000) a[j] = expf(s[q] - mx) * inv;
    }
    if (tid < 24) a[1000 + tid] = 0.f;
    float pr = expf(last - mx) * inv;
    for (int i = tid; i < E; i += 256) a[1024 + i] = pr * sps[i];
    // re-init SCT row to zeros for the next step's split-K accumulation
    for (int n2 = tid; n2 < 1512; n2 += 256) row[n2] = 0.f;
  } else {
    float* so = outp + (size_t)b * (R + 1);
#pragma unroll
    for (int q = 0; q < 4; ++q) {
      int j = tid + q * 256;
      if (j < 1000) so[j] = s[q];
    }
    if (tid == 0) so[R] = last;
  }
}

// ---------- fused merged+GI gemm, split-K atomic, 32-row tiles: grid (24,4,4) ----------
__global__ __launch_bounds__(256) void k_giup(const float* __restrict__ A2,
                                              const float* __restrict__ Wbig,
                                              float* __restrict__ GI,
                                              const int* __restrict__ xdst) {
  __shared__ float As[16][32];
  __shared__ float Ws[16][64];
  int tid = threadIdx.x;
  int nBase = blockIdx.x * 64;
  int mBase = blockIdx.y * 32;
  int kbeg = blockIdx.z * 384;
  int tx = tid & 15, ty = tid >> 4;
  int ar = tid & 31, ak = (tid >> 5) * 2;
  int li = tid & 63, wr = tid >> 6;
  float acc[2][4] = {{0.f,0.f,0.f,0.f},{0.f,0.f,0.f,0.f}};
  const float* Arow = A2 + (size_t)(mBase + ar) * K3;
  for (int k0 = kbeg; k0 < kbeg + 384; k0 += 16) {
    float2 av = *(const float2*)(Arow + k0 + ak);
    As[ak + 0][ar] = av.x; As[ak + 1][ar] = av.y;
#pragma unroll
    for (int j = 0; j < 4; ++j)
      Ws[wr * 4 + j][li] = Wbig[(size_t)(k0 + wr * 4 + j) * K3 + nBase + li];
    __syncthreads();
    TILE_FMA32
    __syncthreads();
  }
#pragma unroll
  for (int r = 0; r < 2; ++r) {
    int mm = mBase + ty * 2 + r;
    size_t crow = (size_t)xdst[mm] * K3;
#pragma unroll
    for (int c = 0; c < 4; ++c) {
      int nn = nBase + tx * 4 + c;
      atomicAdd(&GI[crow + nn], acc[r][c]);
    }
  }
}

extern "C" void kernel_launch(void* const* d_in, const int* in_sizes, int n_in,
                              void* d_out, int out_size, void* d_ws, size_t ws_size,
                              hipStream_t stream) {
  (void)in_sizes; (void)n_in; (void)out_size; (void)ws_size;
  const int* tokens = (const int*)d_in[0];
  const float* emb = (const float*)d_in[1];
  const float* W_ih = (const float*)d_in[2];
  const float* W_hh = (const float*)d_in[3];
  const float* b_ih = (const float*)d_in[4];
  const float* b_hh = (const float*)d_in[5];
  const float* w_fc = (const float*)d_in[6];
  const float* b_fc = (const float*)d_in[7];
  const float* Wq = (const float*)d_in[8];
  const float* bq = (const float*)d_in[9];
  const float* Wk = (const float*)d_in[10];
  const float* bk = (const float*)d_in[11];
  float* out = (float*)d_out;

  float* ws = (float*)d_ws;
  size_t o = 0;
  float* GI = ws + o;    o += (size_t)B * S * K3;
  float* GHCP = ws + o;  o += (size_t)B * S * K3;   // position-keyed W_hh@h1 cache
  float* H1P = ws + o;   o += (size_t)B * S * E;    // position-keyed h1 cache
  float* PAIR = ws + o;  o += (size_t)B * S * E;
  float* Wbig = ws + o;  o += (size_t)K3 * K3;      // [EW(1000) | 0(24) | W_ih^T(512)] k-major
  float* Gbig = ws + o;  o += (size_t)1512 * E;     // [G2(1000) ; Mqk(512)]
  float* KREL = ws + o;  o += (size_t)R * E;
  float* WqT = ws + o;   o += (size_t)E * E;
  float* WkT = ws + o;   o += (size_t)E * E;
  float* SCT = ws + o;   o += (size_t)B * K3;
  float* A2 = ws + o;    o += (size_t)B * K3;
  float* gb = ws + o;    o += 1024;
  float* v12 = ws + o;   o += 512;
  float* c0s = ws + o;   o += 16;
  float* SCR = ws + o;   o += B * 16;
  int* pos0 = (int*)(ws + o); o += B * 16;
  int* pos1 = (int*)(ws + o); o += B * 16;
  int* wlb = (int*)(ws + o);  o += NW0;
  int* wlL = (int*)(ws + o);  o += NW0;
  int* wlR = (int*)(ws + o);  o += NW0;
  int* xdst = (int*)(ws + o); o += B;

  // ---- setup: 5 launches ----
  k_prep<<<336, 256, 0, stream>>>(Wq, Wk, W_ih, WqT, WkT, Wbig, pos0, wlb, wlL, wlR, out);
  // KREL = emb@Wk^T + bk  AND  Wbig[0:1000] = EW = emb@W_ih^T  (one dual-output gemm)
  k_gemmD<<<dim3(32, 16), 256, 0, stream>>>(emb, E, R, Wk, E, bk, KREL, E,
                                            W_ih, K3, Wbig, K3, E);
  // G2/Mqk/misc + GI gather + h1(all 2048 positions) + SCT zero-init
  k_setup3<<<199 + B * S + 8, 256, 0, stream>>>(KREL, WqT, WkT, bq, bk, Gbig, v12, c0s,
                                                gb, tokens, Wbig, b_ih, b_hh, GI, H1P, SCT);
  // GHCP = H1P @ W_hh^T + bhh for all 2048 positions (position-keyed cache)
  k_gemm<<<dim3(24, 32), 256, 0, stream>>>(H1P, E, B * S, W_hh, K3, E, b_hh, 1.f,
                                           GHCP, K3);
  k_pairc<<<NW0, 256, 0, stream>>>(wlb, wlL, wlR, GI, GHCP, H1P, w_fc, b_fc, PAIR, SCR);

  // ---- 14 merge steps, 6 kernels each; only position xdst's h1/GHC recomputed ----
  for (int t = 0; t < 14; ++t) {
    int* pin = (t & 1) ? pos1 : pos0;
    int* pout = (t & 1) ? pos0 : pos1;
    k_qscsel<<<dim3(24, 4, 2), 256, 0, stream>>>(PAIR, SCR, pin, pout, wlb, wlL, wlR,
                                                 xdst, Gbig, SCT, GI, b_ih, 15 - t, 0);
    k_sm<<<B, 256, 0, stream>>>(SCT, PAIR, xdst, v12, c0s, out, A2, gb, t, 0);
    k_giup<<<dim3(24, 4, 4), 256, 0, stream>>>(A2, Wbig, GI, xdst);
    k_h1c<<<B, 256, 0, stream>>>(xdst, GI, b_hh, H1P, GHCP);
    k_ghcs<<<dim3(24, 4, 2), 256, 0, stream>>>(xdst, H1P, W_hh, GHCP);
    k_pairc<<<NWS, 256, 0, stream>>>(wlb, wlL, wlR, GI, GHCP, H1P, w_fc, b_fc, PAIR, SCR);
  }

  // ---- final: h2 = PAIR[b][pos0[b*16]]; attention, scores+loss straight to out ----
  k_qscsel<<<dim3(24, 4, 2), 256, 0, stream>>>(PAIR, SCR, pos0, pos1, wlb, wlL, wlR,
                                               xdst, Gbig, SCT, GI, b_ih, 1, 1);
  k_sm<<<B, 256, 0, stream>>>(SCT, PAIR, xdst, v12, c0s, out, A2, gb, 15, 1);
}

// Round 14
// 1337.154 us; speedup vs baseline: 1.1969x; 1.0157x over previous
//
#include <hip/hip_runtime.h>

#define B 128
#define S 16
#define E 512
#define R 1000
#define K3 1536
#define NW0 1920   // init worklist: 128 b * 15 pairs
#define NWS 256    // per-step worklist: 128 b * 2 entries
#define NS (B * (R + 1))
#define SCALE 0.04419417382415922f

static __device__ __forceinline__ float sigm(float x) { return 1.f / (1.f + expf(-x)); }

// ---------- block reductions (256 threads) ----------
static __device__ __forceinline__ float brsum(float v, float* sb) {
  int tid = threadIdx.x;
  sb[tid] = v; __syncthreads();
  for (int s = 128; s > 0; s >>= 1) {
    if (tid < s) sb[tid] += sb[tid + s];
    __syncthreads();
  }
  float r = sb[0]; __syncthreads();
  return r;
}
static __device__ __forceinline__ float brmax(float v, float* sb) {
  int tid = threadIdx.x;
  sb[tid] = v; __syncthreads();
  for (int s = 128; s > 0; s >>= 1) {
    if (tid < s) sb[tid] = fmaxf(sb[tid], sb[tid + s]);
    __syncthreads();
  }
  float r = sb[0]; __syncthreads();
  return r;
}
// paired sum reduction: (v1,v2) -> (sb[0], sb2[0])
static __device__ __forceinline__ void brsum2(float v1, float v2, float* sb, float* sb2,
                                              float* o1, float* o2) {
  int tid = threadIdx.x;
  sb[tid] = v1; sb2[tid] = v2; __syncthreads();
  for (int s = 128; s > 0; s >>= 1) {
    if (tid < s) { sb[tid] += sb[tid + s]; sb2[tid] += sb2[tid + s]; }
    __syncthreads();
  }
  *o1 = sb[0]; *o2 = sb2[0]; __syncthreads();
}

#define TILE_FMA \
  _Pragma("unroll") \
  for (int k = 0; k < 16; ++k) { \
    float4 a4 = *(const float4*)&As[k][ty * 4]; \
    float4 w4 = *(const float4*)&Ws[k][tx * 4]; \
    acc[0][0] = fmaf(a4.x, w4.x, acc[0][0]); acc[0][1] = fmaf(a4.x, w4.y, acc[0][1]); \
    acc[0][2] = fmaf(a4.x, w4.z, acc[0][2]); acc[0][3] = fmaf(a4.x, w4.w, acc[0][3]); \
    acc[1][0] = fmaf(a4.y, w4.x, acc[1][0]); acc[1][1] = fmaf(a4.y, w4.y, acc[1][1]); \
    acc[1][2] = fmaf(a4.y, w4.z, acc[1][2]); acc[1][3] = fmaf(a4.y, w4.w, acc[1][3]); \
    acc[2][0] = fmaf(a4.z, w4.x, acc[2][0]); acc[2][1] = fmaf(a4.z, w4.y, acc[2][1]); \
    acc[2][2] = fmaf(a4.z, w4.z, acc[2][2]); acc[2][3] = fmaf(a4.z, w4.w, acc[2][3]); \
    acc[3][0] = fmaf(a4.w, w4.x, acc[3][0]); acc[3][1] = fmaf(a4.w, w4.y, acc[3][1]); \
    acc[3][2] = fmaf(a4.w, w4.z, acc[3][2]); acc[3][3] = fmaf(a4.w, w4.w, acc[3][3]); \
  }

// 32-row-tile inner product: acc[2][4], A in As[16][32], W in Ws[16][64]
#define TILE_FMA32 \
  _Pragma("unroll") \
  for (int k = 0; k < 16; ++k) { \
    float2 a2 = *(const float2*)&As[k][ty * 2]; \
    float4 w4 = *(const float4*)&Ws[k][tx * 4]; \
    acc[0][0] = fmaf(a2.x, w4.x, acc[0][0]); acc[0][1] = fmaf(a2.x, w4.y, acc[0][1]); \
    acc[0][2] = fmaf(a2.x, w4.z, acc[0][2]); acc[0][3] = fmaf(a2.x, w4.w, acc[0][3]); \
    acc[1][0] = fmaf(a2.y, w4.x, acc[1][0]); acc[1][1] = fmaf(a2.y, w4.y, acc[1][1]); \
    acc[1][2] = fmaf(a2.y, w4.z, acc[1][2]); acc[1][3] = fmaf(a2.y, w4.w, acc[1][3]); \
  }

// ---------- generic tiled gemm (standalone body — VGPR~44 codegen) ----------
__global__ __launch_bounds__(256) void k_gemm(const float* __restrict__ A, int lda, int M,
                                              const float* __restrict__ W, int N, int K,
                                              const float* __restrict__ bias, float scale,
                                              float* __restrict__ C, int ldc) {
  __shared__ float As[16][64];
  __shared__ float Ws[16][64];
  int tid = threadIdx.x;
  int mBase = blockIdx.y * 64;
  int nBase = blockIdx.x * 64;
  int tx = tid & 15, ty = tid >> 4;
  int li = tid & 63;
  int lk = (tid >> 6) * 4;
  float acc[4][4] = {{0.f,0.f,0.f,0.f},{0.f,0.f,0.f,0.f},{0.f,0.f,0.f,0.f},{0.f,0.f,0.f,0.f}};
  int m = mBase + li;
  const float* Arow = (m < M) ? (A + (size_t)m * lda) : nullptr;
  int n = nBase + li;
  const float* Wrow = (n < N) ? (W + (size_t)n * K) : nullptr;

  float4 av = Arow ? *(const float4*)(Arow + lk) : make_float4(0.f, 0.f, 0.f, 0.f);
  float4 wv = Wrow ? *(const float4*)(Wrow + lk) : make_float4(0.f, 0.f, 0.f, 0.f);

  for (int k0 = 0; k0 < K; k0 += 16) {
    As[lk + 0][li] = av.x; As[lk + 1][li] = av.y;
    As[lk + 2][li] = av.z; As[lk + 3][li] = av.w;
    Ws[lk + 0][li] = wv.x; Ws[lk + 1][li] = wv.y;
    Ws[lk + 2][li] = wv.z; Ws[lk + 3][li] = wv.w;
    __syncthreads();
    if (k0 + 16 < K) {
      av = Arow ? *(const float4*)(Arow + k0 + 16 + lk) : make_float4(0.f, 0.f, 0.f, 0.f);
      wv = Wrow ? *(const float4*)(Wrow + k0 + 16 + lk) : make_float4(0.f, 0.f, 0.f, 0.f);
    }
    TILE_FMA
    __syncthreads();
  }
#pragma unroll
  for (int r = 0; r < 4; ++r) {
    int mm = mBase + ty * 4 + r;
    if (mm >= M) continue;
#pragma unroll
    for (int c = 0; c < 4; ++c) {
      int nn = nBase + tx * 4 + c;
      if (nn >= N) continue;
      float v = acc[r][c] * scale;
      if (bias) v += bias[nn];
      C[(size_t)mm * ldc + nn] = v;
    }
  }
}

// ---------- dual-output gemm: n<N1 -> W1,b1,C1 ; else W2,C2 (no bias) ----------
__global__ __launch_bounds__(256) void k_gemmD(const float* __restrict__ A, int lda, int M,
                                               const float* __restrict__ W1, int N1,
                                               const float* __restrict__ b1,
                                               float* __restrict__ C1, int ldc1,
                                               const float* __restrict__ W2, int N2,
                                               float* __restrict__ C2, int ldc2, int K) {
  __shared__ float As[16][64];
  __shared__ float Ws[16][64];
  int tid = threadIdx.x;
  int mBase = blockIdx.y * 64;
  int nBase = blockIdx.x * 64;
  int tx = tid & 15, ty = tid >> 4;
  int li = tid & 63;
  int lk = (tid >> 6) * 4;
  float acc[4][4] = {{0.f,0.f,0.f,0.f},{0.f,0.f,0.f,0.f},{0.f,0.f,0.f,0.f},{0.f,0.f,0.f,0.f}};
  int m = mBase + li;
  const float* Arow = (m < M) ? (A + (size_t)m * lda) : nullptr;
  int n = nBase + li;
  const float* Wrow = nullptr;
  if (n < N1) Wrow = W1 + (size_t)n * K;
  else if (n < N1 + N2) Wrow = W2 + (size_t)(n - N1) * K;

  float4 av = Arow ? *(const float4*)(Arow + lk) : make_float4(0.f, 0.f, 0.f, 0.f);
  float4 wv = Wrow ? *(const float4*)(Wrow + lk) : make_float4(0.f, 0.f, 0.f, 0.f);

  for (int k0 = 0; k0 < K; k0 += 16) {
    As[lk + 0][li] = av.x; As[lk + 1][li] = av.y;
    As[lk + 2][li] = av.z; As[lk + 3][li] = av.w;
    Ws[lk + 0][li] = wv.x; Ws[lk + 1][li] = wv.y;
    Ws[lk + 2][li] = wv.z; Ws[lk + 3][li] = wv.w;
    __syncthreads();
    if (k0 + 16 < K) {
      av = Arow ? *(const float4*)(Arow + k0 + 16 + lk) : make_float4(0.f, 0.f, 0.f, 0.f);
      wv = Wrow ? *(const float4*)(Wrow + k0 + 16 + lk) : make_float4(0.f, 0.f, 0.f, 0.f);
    }
    TILE_FMA
    __syncthreads();
  }
#pragma unroll
  for (int r = 0; r < 4; ++r) {
    int mm = mBase + ty * 4 + r;
    if (mm >= M) continue;
#pragma unroll
    for (int c = 0; c < 4; ++c) {
      int nn = nBase + tx * 4 + c;
      if (nn < N1) {
        float v = acc[r][c];
        if (b1) v += b1[nn];
        C1[(size_t)mm * ldc1 + nn] = v;
      } else if (nn < N1 + N2) {
        C2[(size_t)mm * ldc2 + (nn - N1)] = acc[r][c];
      }
    }
  }
}

// ---------- 64x64 gemm core for setup3 only ----------
static __device__ void dev_g64(float (*As)[64], float (*Ws)[64], int tid,
                               int mBase, int nBase,
                               const float* __restrict__ A, int lda, int M,
                               const float* __restrict__ W, int N, int K,
                               const float* __restrict__ bias, float scale,
                               float* __restrict__ C, int ldc) {
  int tx = tid & 15, ty = tid >> 4;
  int li = tid & 63;
  int lk = (tid >> 6) * 4;
  float acc[4][4] = {{0.f,0.f,0.f,0.f},{0.f,0.f,0.f,0.f},{0.f,0.f,0.f,0.f},{0.f,0.f,0.f,0.f}};
  int m = mBase + li;
  const float* Arow = (m < M) ? (A + (size_t)m * lda) : nullptr;
  int n = nBase + li;
  const float* Wrow = (n < N) ? (W + (size_t)n * K) : nullptr;

  float4 av = Arow ? *(const float4*)(Arow + lk) : make_float4(0.f, 0.f, 0.f, 0.f);
  float4 wv = Wrow ? *(const float4*)(Wrow + lk) : make_float4(0.f, 0.f, 0.f, 0.f);

  for (int k0 = 0; k0 < K; k0 += 16) {
    As[lk + 0][li] = av.x; As[lk + 1][li] = av.y;
    As[lk + 2][li] = av.z; As[lk + 3][li] = av.w;
    Ws[lk + 0][li] = wv.x; Ws[lk + 1][li] = wv.y;
    Ws[lk + 2][li] = wv.z; Ws[lk + 3][li] = wv.w;
    __syncthreads();
    if (k0 + 16 < K) {
      av = Arow ? *(const float4*)(Arow + k0 + 16 + lk) : make_float4(0.f, 0.f, 0.f, 0.f);
      wv = Wrow ? *(const float4*)(Wrow + k0 + 16 + lk) : make_float4(0.f, 0.f, 0.f, 0.f);
    }
    TILE_FMA
    __syncthreads();
  }
#pragma unroll
  for (int r = 0; r < 4; ++r) {
    int mm = mBase + ty * 4 + r;
    if (mm >= M) continue;
#pragma unroll
    for (int c = 0; c < 4; ++c) {
      int nn = nBase + tx * 4 + c;
      if (nn >= N) continue;
      float v = acc[r][c] * scale;
      if (bias) v += bias[nn];
      C[(size_t)mm * ldc + nn] = v;
    }
  }
}

// ---------- 64x64 transpose tile (device) ----------
static __device__ void dev_tr64(float (*t)[65], int tid, const float* __restrict__ src,
                                int Cc, float* __restrict__ dst, int ldd, int bx, int by) {
  int tx = tid & 15, ty = tid >> 4;
  int rb = by * 64, cb = bx * 64;
#pragma unroll
  for (int i = 0; i < 4; ++i) {
    int r = rb + ty + i * 16;
    float4 v = *(const float4*)(src + (size_t)r * Cc + cb + tx * 4);
    t[ty + i * 16][tx * 4 + 0] = v.x; t[ty + i * 16][tx * 4 + 1] = v.y;
    t[ty + i * 16][tx * 4 + 2] = v.z; t[ty + i * 16][tx * 4 + 3] = v.w;
  }
  __syncthreads();
#pragma unroll
  for (int i = 0; i < 4; ++i) {
    int c = cb + ty + i * 16;
    float4 v;
    v.x = t[tx * 4 + 0][ty + i * 16]; v.y = t[tx * 4 + 1][ty + i * 16];
    v.z = t[tx * 4 + 2][ty + i * 16]; v.w = t[tx * 4 + 3][ty + i * 16];
    *(float4*)(dst + (size_t)c * ldd + rb + tx * 4) = v;
  }
}

// ---------- setup L1: transposes + initwl + Wbig pad + out col14 zero ----------
__global__ __launch_bounds__(256) void k_prep(const float* __restrict__ Wq,
                                              const float* __restrict__ Wk,
                                              const float* __restrict__ Wih,
                                              float* __restrict__ WqT,
                                              float* __restrict__ WkT,
                                              float* __restrict__ Wbig,
                                              int* __restrict__ pos,
                                              int* __restrict__ wlb,
                                              int* __restrict__ wlL,
                                              int* __restrict__ wlR,
                                              float* __restrict__ outp) {
  __shared__ float t[64][65];
  int blk = blockIdx.x, tid = threadIdx.x;
  if (blk < 64) {
    dev_tr64(t, tid, Wq, E, WqT, E, blk & 7, blk >> 3);
  } else if (blk < 128) {
    int j = blk - 64;
    dev_tr64(t, tid, Wk, E, WkT, E, j & 7, j >> 3);
  } else if (blk < 320) {
    int j = blk - 128;
    dev_tr64(t, tid, Wih, E, Wbig + (size_t)1024 * K3, K3, j & 7, j >> 3);
  } else if (blk < 328) {
    int idx = (blk - 320) * 256 + tid;
    if (idx < B * 16) pos[idx] = idx & 15;
    if (idx < NW0) {
      wlb[idx] = idx / 15;
      int i = idx % 15;
      wlL[idx] = i;
      wlR[idx] = i + 1;
    }
    if (idx < B) outp[NS + idx * 16 + 14] = 0.f;  // loss col 14 is identically 0
  } else {
    int idx = (blk - 328) * 256 + tid;
    for (int i = idx; i < 24 * K3; i += 8 * 256) Wbig[(size_t)1000 * K3 + i] = 0.f;
  }
}

// ---------- setup L3: G2 [0,128) | Mqk [128,192) | misc [192,199)
//            | GI gather + h1 all positions [199,199+2048) | SCT zero [2247,2255) ----------
__global__ __launch_bounds__(256) void k_setup3(const float* __restrict__ KREL,
                                                const float* __restrict__ WqT,
                                                const float* __restrict__ WkT,
                                                const float* __restrict__ bq,
                                                const float* __restrict__ bk,
                                                float* __restrict__ Gbig,
                                                float* __restrict__ v12,
                                                float* __restrict__ c0s,
                                                float* __restrict__ gb,
                                                const int* __restrict__ tokens,
                                                const float* __restrict__ Wbig,
                                                const float* __restrict__ bih,
                                                const float* __restrict__ bhh,
                                                float* __restrict__ GI,
                                                float* __restrict__ H1P,
                                                float* __restrict__ SCT) {
  __shared__ float As[16][64];
  __shared__ float Ws[16][64];
  int blk = blockIdx.x, tid = threadIdx.x;
  if (blk < 128) {
    dev_g64(As, Ws, tid, (blk >> 3) * 64, (blk & 7) * 64, KREL, E, R, WqT, E, E,
            nullptr, 1.f, Gbig, E);
  } else if (blk < 192) {
    int j = blk - 128;
    dev_g64(As, Ws, tid, (j >> 3) * 64, (j & 7) * 64, WqT, E, E, WkT, E, E,
            nullptr, 1.f, Gbig + (size_t)1000 * E, E);
  } else if (blk < 199) {
    int m = blk - 192;
    if (m < 2) {
      int i = m * 256 + tid;
      const float* wq = WqT + (size_t)i * E;
      const float* wk = WkT + (size_t)i * E;
      float s = 0.f;
      for (int e = 0; e < E; ++e) s += wq[e] * bk[e] + bq[e] * wk[e];
      v12[i] = s;
    } else if (m == 2) {
      float* sb = (float*)As;
      float p = 0.f;
      for (int e = tid; e < E; e += 256) p += bq[e] * bk[e];
      float s = brsum(p, sb);
      if (tid == 0) c0s[0] = s;
    } else {
      int r = (m - 3) * 256 + tid;
      if (r < R) {
        const float* kr = KREL + (size_t)r * E;
        float s = 0.f;
        for (int e = 0; e < E; ++e) s += bq[e] * kr[e];
        gb[r] = s;
      }
    }
  } else if (blk < 199 + B * S) {
    int row = blk - 199;
    int tok = tokens[row];
    const float4* src = (const float4*)(Wbig + (size_t)tok * K3);
    const float4* bv = (const float4*)bih;
    float* girow = GI + (size_t)row * K3;
    float4* dst = (float4*)girow;
    for (int i = tid; i < K3 / 4; i += 256) {
      float4 a = src[i], b = bv[i];
      dst[i] = make_float4(a.x + b.x, a.y + b.y, a.z + b.z, a.w + b.w);
    }
    __syncthreads();  // GI row visible (this block's own writes)
    float* h = H1P + (size_t)row * E;
    for (int e = tid; e < E; e += 256) {
      float r = sigm(girow[e] + bhh[e]);
      float z = sigm(girow[E + e] + bhh[E + e]);
      h[e] = (1.f - z) * tanhf(girow[2 * E + e] + r * bhh[2 * E + e]);
    }
  } else {
    int rb = blk - (199 + B * S);  // 0..7 -> 16 SCT rows each
    for (int m = rb * 16; m < rb * 16 + 16; ++m) {
      float* r = SCT + (size_t)m * K3;
      for (int n = tid; n < 1512; n += 256) r[n] = 0.f;
    }
  }
}

// ---------- per-step h1: one block per batch; recompute position xdst[b] ----------
__global__ __launch_bounds__(256) void k_h1c(const int* __restrict__ xdst,
                                             const float* __restrict__ GI,
                                             const float* __restrict__ bhh,
                                             float* __restrict__ H1P) {
  int p = xdst[blockIdx.x], tid = threadIdx.x;
  const float* gi = GI + (size_t)p * K3;
  float* h = H1P + (size_t)p * E;
  for (int e = tid; e < E; e += 256) {
    float r = sigm(gi[e] + bhh[e]);
    float z = sigm(gi[E + e] + bhh[E + e]);
    h[e] = (1.f - z) * tanhf(gi[2 * E + e] + r * bhh[2 * E + e]);
  }
}

// ---------- GHC split-K gemm, 32-row tiles, position-indirect: grid (24, 4, 2) ----------
// GHCP[xdst[m], n] += H1P[xdst[m], kslice] . Whh[n, kslice]; pre-initialized with bhh
__global__ __launch_bounds__(256) void k_ghcs(const int* __restrict__ xdst,
                                              const float* __restrict__ H1P,
                                              const float* __restrict__ Whh,
                                              float* __restrict__ GHCP) {
  __shared__ float As[16][32];
  __shared__ float Ws[16][64];
  __shared__ int sp[32];
  int tid = threadIdx.x;
  int nBase = blockIdx.x * 64;
  int mBase = blockIdx.y * 32;
  int kbeg = blockIdx.z * 256;
  if (tid < 32) sp[tid] = xdst[mBase + tid];
  __syncthreads();
  int tx = tid & 15, ty = tid >> 4;
  int ar = tid & 31, ak = (tid >> 5) * 2;
  int li = tid & 63, lk = (tid >> 6) * 4;
  float acc[2][4] = {{0.f,0.f,0.f,0.f},{0.f,0.f,0.f,0.f}};
  const float* Arow = H1P + (size_t)sp[ar] * E + kbeg;
  const float* Wrow = Whh + (size_t)(nBase + li) * E + kbeg;
  float2 av = *(const float2*)(Arow + ak);
  float4 wv = *(const float4*)(Wrow + lk);
  for (int k0 = 0; k0 < 256; k0 += 16) {
    As[ak + 0][ar] = av.x; As[ak + 1][ar] = av.y;
    Ws[lk + 0][li] = wv.x; Ws[lk + 1][li] = wv.y;
    Ws[lk + 2][li] = wv.z; Ws[lk + 3][li] = wv.w;
    __syncthreads();
    if (k0 + 16 < 256) {
      av = *(const float2*)(Arow + k0 + 16 + ak);
      wv = *(const float4*)(Wrow + k0 + 16 + lk);
    }
    TILE_FMA32
    __syncthreads();
  }
#pragma unroll
  for (int r = 0; r < 2; ++r) {
    size_t crow = (size_t)sp[ty * 2 + r] * K3;
#pragma unroll
    for (int c = 0; c < 4; ++c) {
      int nn = nBase + tx * 4 + c;
      atomicAdd(&GHCP[crow + nn], acc[r][c]);
    }
  }
}

// ---------- pair + fc score (position-keyed H1P/GHCP caches) ----------
__global__ __launch_bounds__(256) void k_pairc(const int* __restrict__ wlb,
                                               const int* __restrict__ wlL,
                                               const int* __restrict__ wlR,
                                               const float* __restrict__ GI,
                                               const float* __restrict__ GHCP,
                                               const float* __restrict__ H1P,
                                               const float* __restrict__ wfc,
                                               const float* __restrict__ bfc,
                                               float* __restrict__ PAIR,
                                               float* __restrict__ SCR) {
  __shared__ float sb[256];
  int w = blockIdx.x, tid = threadIdx.x;
  int b = wlb[w], ls = wlL[w], rs = wlR[w];
  int lp = b * 16 + ls;
  const float* gr = GI + (size_t)(b * 16 + rs) * K3;
  const float* gh = GHCP + (size_t)lp * K3;
  const float* h = H1P + (size_t)lp * E;
  float* p = PAIR + (size_t)lp * E;
  float part = 0.f;
  for (int e = tid; e < E; e += 256) {
    float r = sigm(gr[e] + gh[e]);
    float z = sigm(gr[E + e] + gh[E + e]);
    float n = tanhf(gr[2 * E + e] + r * gh[2 * E + e]);
    float pv = (1.f - z) * n + z * h[e];
    p[e] = pv;
    part += pv * wfc[e];
  }
  float d = brsum(part, sb);
  if (tid == 0) SCR[b * 16 + ls] = sigm(d + bfc[0]);
}

// ---------- fused sel + scores split-K gemm, 32-row tiles: grid (24, 4, 2) ----------
// Block (0, y, 0) writes pos/wl/xdst; z==1: x<16 write GI[xdst]=bih (2 rows each),
// x in [16,24) write GHCP[xdst]=bhh (4 rows each).
__global__ __launch_bounds__(256) void k_qscsel(const float* __restrict__ PAIR,
                                                const float* __restrict__ SCR,
                                                const int* __restrict__ pin,
                                                int* __restrict__ pout,
                                                int* __restrict__ wlb,
                                                int* __restrict__ wlL,
                                                int* __restrict__ wlR,
                                                int* __restrict__ xdst,
                                                const float* __restrict__ Gbig,
                                                float* __restrict__ SCT,
                                                float* __restrict__ GI,
                                                const float* __restrict__ bih,
                                                float* __restrict__ GHCP,
                                                const float* __restrict__ bhh,
                                                int P, int finalMode) {
  __shared__ float As[16][32];
  __shared__ float Ws[16][64];
  __shared__ int sxd[32];
  int tid = threadIdx.x;
  int nBase = blockIdx.x * 64;
  int mBase = blockIdx.y * 32;
  int kbeg = blockIdx.z * 256;
  if (tid < 32) {
    int b = mBase + tid;
    if (finalMode) {
      int xr = b * 16 + pin[b * 16];
      sxd[tid] = xr;
      if (blockIdx.x == 0 && blockIdx.z == 0) xdst[b] = xr;
    } else {
      int L = P + 1;
      int lp[16];
      for (int i = 0; i < L; ++i) lp[i] = pin[b * 16 + i];
      float best = -1e30f; int sel = 0;
      for (int i = 0; i < P; ++i) {
        float v = SCR[b * 16 + lp[i]];
        if (v > best) { best = v; sel = i; }
      }
      int r1i = (sel + 2 < L) ? sel + 2 : L - 1;
      int l1 = lp[sel], r1 = lp[r1i];
      int l0 = (sel > 0) ? lp[sel - 1] : l1;
      int r0 = (sel > 0) ? lp[sel] : r1;
      sxd[tid] = b * 16 + l1;
      if (blockIdx.x == 0 && blockIdx.z == 0) {
        wlb[2 * b] = b;     wlL[2 * b] = l0;     wlR[2 * b] = r0;
        wlb[2 * b + 1] = b; wlL[2 * b + 1] = l1; wlR[2 * b + 1] = r1;
        xdst[b] = b * 16 + l1;
        for (int i = 0; i < L - 1; ++i)
          pout[b * 16 + i] = (i <= sel) ? lp[i] : lp[i + 1];
      }
    }
  }
  __syncthreads();
  // Early cache-row inits, off the k_sm/k_h1c critical paths (duplicate-safe writes):
  // old GI[xdst]/GHCP[xdst] values have no readers after this point this step.
  if (!finalMode && blockIdx.z == 1) {
    if (blockIdx.x < 16) {
#pragma unroll
      for (int r = 0; r < 2; ++r) {
        float* g = GI + (size_t)sxd[blockIdx.x * 2 + r] * K3;
        for (int i = tid; i < K3; i += 256) g[i] = bih[i];
      }
    } else {
#pragma unroll
      for (int r = 0; r < 4; ++r) {
        float* g = GHCP + (size_t)sxd[(blockIdx.x - 16) * 4 + r] * K3;
        for (int i = tid; i < K3; i += 256) g[i] = bhh[i];
      }
    }
  }
  int tx = tid & 15, ty = tid >> 4;
  int ar = tid & 31, ak = (tid >> 5) * 2;
  int li = tid & 63, lk = (tid >> 6) * 4;
  float acc[2][4] = {{0.f,0.f,0.f,0.f},{0.f,0.f,0.f,0.f}};
  const float* Arow = PAIR + (size_t)sxd[ar] * E + kbeg;
  int n = nBase + li;
  const float* Wrow = (n < 1512) ? (Gbig + (size_t)n * E + kbeg) : nullptr;
  float2 av = *(const float2*)(Arow + ak);
  float4 wv = Wrow ? *(const float4*)(Wrow + lk) : make_float4(0.f, 0.f, 0.f, 0.f);
  for (int k0 = 0; k0 < 256; k0 += 16) {
    As[ak + 0][ar] = av.x; As[ak + 1][ar] = av.y;
    Ws[lk + 0][li] = wv.x; Ws[lk + 1][li] = wv.y;
    Ws[lk + 2][li] = wv.z; Ws[lk + 3][li] = wv.w;
    __syncthreads();
    if (k0 + 16 < 256) {
      av = *(const float2*)(Arow + k0 + 16 + ak);
      wv = Wrow ? *(const float4*)(Wrow + k0 + 16 + lk) : make_float4(0.f, 0.f, 0.f, 0.f);
    }
    TILE_FMA32
    __syncthreads();
  }
#pragma unroll
  for (int r = 0; r < 2; ++r) {
    int mm = mBase + ty * 2 + r;
#pragma unroll
    for (int c = 0; c < 4; ++c) {
      int nn = nBase + tx * 4 + c;
      if (nn < 1512) atomicAdd(&SCT[(size_t)mm * K3 + nn], acc[r][c]);
    }
  }
}

// ---------- softmax/entropy + A2 build + SCT re-init (zeros) ----------
// SCT holds RAW dots (zero-init); gb added here. losses/(final) scores straight to out.
__global__ __launch_bounds__(256) void k_sm(float* __restrict__ SCT,
                                            const float* __restrict__ PAIR,
                                            const int* __restrict__ xdst,
                                            const float* __restrict__ v12,
                                            const float* __restrict__ c0s,
                                            float* __restrict__ outp,
                                            float* __restrict__ A2,
                                            const float* __restrict__ gb,
                                            int t, int finalMode) {
  __shared__ float sb[256];
  __shared__ float sb2[256];
  __shared__ float sps[E];
  int b = blockIdx.x, tid = threadIdx.x;
  float* row = SCT + (size_t)b * K3;
  int xr = xdst[b];
  const float* sp = PAIR + (size_t)xr * E;
  for (int i = tid; i < E; i += 256) sps[i] = sp[i];
  __syncthreads();
  // bilinear self-score: raw Mqk part in cols 1000..1511
  float part = 0.f;
  for (int i = tid; i < E; i += 256) part += sps[i] * (row[1000 + i] + v12[i]);
  float last = (brsum(part, sb) + c0s[0]) * SCALE;
  float s[4];
  float ml = last;
#pragma unroll
  for (int q = 0; q < 4; ++q) {
    int j = tid + q * 256;
    s[q] = (j < 1000) ? (row[j] + gb[j]) * SCALE : -1e30f;  // raw dot + gb
    ml = fmaxf(ml, s[q]);
  }
  float mx = brmax(ml, sb);
  float zp = 0.f, s1p = 0.f;
#pragma unroll
  for (int q = 0; q < 4; ++q) {
    int j = tid + q * 256;
    if (j < 1000) { float e = expf(s[q] - mx); zp += e; s1p += e * s[q]; }
  }
  if (tid == 0) { float e = expf(last - mx); zp += e; s1p += e * last; }
  float z, s1;
  brsum2(zp, s1p, sb, sb2, &z, &s1);
  if (tid == 0) outp[NS + b * 16 + t] = mx + logf(z) - s1 / z;
  if (!finalMode) {
    float inv = 1.f / z;
    float* a = A2 + (size_t)b * K3;
#pragma unroll
    for (int q = 0; q < 4; ++q) {
      int j = tid + q * 256;
      if (j < 1000) a[j] = expf(s[q] - mx) * inv;
    }
    if (tid < 24) a[1000 + tid] = 0.f;
    float pr = expf(last - mx) * inv;
    for (int i = tid; i < E; i += 256) a[1024 + i] = pr * sps[i];
    // re-init SCT row to zeros for the next step's split-K accumulation
    for (int n2 = tid; n2 < 1512; n2 += 256) row[n2] = 0.f;
  } else {
    float* so = outp + (size_t)b * (R + 1);
#pragma unroll
    for (int q = 0; q < 4; ++q) {
      int j = tid + q * 256;
      if (j < 1000) so[j] = s[q];
    }
    if (tid == 0) so[R] = last;
  }
}

// ---------- fused merged+GI gemm, split-K atomic, 32-row tiles, reg-prefetch:
// grid (24,4,4) ----------
__global__ __launch_bounds__(256) void k_giup(const float* __restrict__ A2,
                                              const float* __restrict__ Wbig,
                                              float* __restrict__ GI,
                                              const int* __restrict__ xdst) {
  __shared__ float As[16][32];
  __shared__ float Ws[16][64];
  int tid = threadIdx.x;
  int nBase = blockIdx.x * 64;
  int mBase = blockIdx.y * 32;
  int kbeg = blockIdx.z * 384;
  int kend = kbeg + 384;
  int tx = tid & 15, ty = tid >> 4;
  int ar = tid & 31, ak = (tid >> 5) * 2;
  int li = tid & 63, wr = tid >> 6;
  float acc[2][4] = {{0.f,0.f,0.f,0.f},{0.f,0.f,0.f,0.f}};
  const float* Arow = A2 + (size_t)(mBase + ar) * K3;
  float2 av = *(const float2*)(Arow + kbeg + ak);
  float w0 = Wbig[(size_t)(kbeg + wr * 4 + 0) * K3 + nBase + li];
  float w1 = Wbig[(size_t)(kbeg + wr * 4 + 1) * K3 + nBase + li];
  float w2 = Wbig[(size_t)(kbeg + wr * 4 + 2) * K3 + nBase + li];
  float w3 = Wbig[(size_t)(kbeg + wr * 4 + 3) * K3 + nBase + li];
  for (int k0 = kbeg; k0 < kend; k0 += 16) {
    As[ak + 0][ar] = av.x; As[ak + 1][ar] = av.y;
    Ws[wr * 4 + 0][li] = w0; Ws[wr * 4 + 1][li] = w1;
    Ws[wr * 4 + 2][li] = w2; Ws[wr * 4 + 3][li] = w3;
    __syncthreads();
    if (k0 + 16 < kend) {  // register prefetch of next tile
      av = *(const float2*)(Arow + k0 + 16 + ak);
      w0 = Wbig[(size_t)(k0 + 16 + wr * 4 + 0) * K3 + nBase + li];
      w1 = Wbig[(size_t)(k0 + 16 + wr * 4 + 1) * K3 + nBase + li];
      w2 = Wbig[(size_t)(k0 + 16 + wr * 4 + 2) * K3 + nBase + li];
      w3 = Wbig[(size_t)(k0 + 16 + wr * 4 + 3) * K3 + nBase + li];
    }
    TILE_FMA32
    __syncthreads();
  }
#pragma unroll
  for (int r = 0; r < 2; ++r) {
    int mm = mBase + ty * 2 + r;
    size_t crow = (size_t)xdst[mm] * K3;
#pragma unroll
    for (int c = 0; c < 4; ++c) {
      int nn = nBase + tx * 4 + c;
      atomicAdd(&GI[crow + nn], acc[r][c]);
    }
  }
}

extern "C" void kernel_launch(void* const* d_in, const int* in_sizes, int n_in,
                              void* d_out, int out_size, void* d_ws, size_t ws_size,
                              hipStream_t stream) {
  (void)in_sizes; (void)n_in; (void)out_size; (void)ws_size;
  const int* tokens = (const int*)d_in[0];
  const float* emb = (const float*)d_in[1];
  const float* W_ih = (const float*)d_in[2];
  const float* W_hh = (const float*)d_in[3];
  const float* b_ih = (const float*)d_in[4];
  const float* b_hh = (const float*)d_in[5];
  const float* w_fc = (const float*)d_in[6];
  const float* b_fc = (const float*)d_in[7];
  const float* Wq = (const float*)d_in[8];
  const float* bq = (const float*)d_in[9];
  const float* Wk = (const float*)d_in[10];
  const float* bk = (const float*)d_in[11];
  float* out = (float*)d_out;

  float* ws = (float*)d_ws;
  size_t o = 0;
  float* GI = ws + o;    o += (size_t)B * S * K3;
  float* GHCP = ws + o;  o += (size_t)B * S * K3;   // position-keyed W_hh@h1 cache
  float* H1P = ws + o;   o += (size_t)B * S * E;    // position-keyed h1 cache
  float* PAIR = ws + o;  o += (size_t)B * S * E;
  float* Wbig = ws + o;  o += (size_t)K3 * K3;      // [EW(1000) | 0(24) | W_ih^T(512)] k-major
  float* Gbig = ws + o;  o += (size_t)1512 * E;     // [G2(1000) ; Mqk(512)]
  float* KREL = ws + o;  o += (size_t)R * E;
  float* WqT = ws + o;   o += (size_t)E * E;
  float* WkT = ws + o;   o += (size_t)E * E;
  float* SCT = ws + o;   o += (size_t)B * K3;
  float* A2 = ws + o;    o += (size_t)B * K3;
  float* gb = ws + o;    o += 1024;
  float* v12 = ws + o;   o += 512;
  float* c0s = ws + o;   o += 16;
  float* SCR = ws + o;   o += B * 16;
  int* pos0 = (int*)(ws + o); o += B * 16;
  int* pos1 = (int*)(ws + o); o += B * 16;
  int* wlb = (int*)(ws + o);  o += NW0;
  int* wlL = (int*)(ws + o);  o += NW0;
  int* wlR = (int*)(ws + o);  o += NW0;
  int* xdst = (int*)(ws + o); o += B;

  // ---- setup: 5 launches ----
  k_prep<<<336, 256, 0, stream>>>(Wq, Wk, W_ih, WqT, WkT, Wbig, pos0, wlb, wlL, wlR, out);
  // KREL = emb@Wk^T + bk  AND  Wbig[0:1000] = EW = emb@W_ih^T  (one dual-output gemm)
  k_gemmD<<<dim3(32, 16), 256, 0, stream>>>(emb, E, R, Wk, E, bk, KREL, E,
                                            W_ih, K3, Wbig, K3, E);
  // G2/Mqk/misc + GI gather + h1(all 2048 positions) + SCT zero-init
  k_setup3<<<199 + B * S + 8, 256, 0, stream>>>(KREL, WqT, WkT, bq, bk, Gbig, v12, c0s,
                                                gb, tokens, Wbig, b_ih, b_hh, GI, H1P, SCT);
  // GHCP = H1P @ W_hh^T + bhh for all 2048 positions (position-keyed cache)
  k_gemm<<<dim3(24, 32), 256, 0, stream>>>(H1P, E, B * S, W_hh, K3, E, b_hh, 1.f,
                                           GHCP, K3);
  k_pairc<<<NW0, 256, 0, stream>>>(wlb, wlL, wlR, GI, GHCP, H1P, w_fc, b_fc, PAIR, SCR);

  // ---- 14 merge steps, 6 kernels each; only position xdst's h1/GHC recomputed ----
  for (int t = 0; t < 14; ++t) {
    int* pin = (t & 1) ? pos1 : pos0;
    int* pout = (t & 1) ? pos0 : pos1;
    k_qscsel<<<dim3(24, 4, 2), 256, 0, stream>>>(PAIR, SCR, pin, pout, wlb, wlL, wlR,
                                                 xdst, Gbig, SCT, GI, b_ih, GHCP, b_hh,
                                                 15 - t, 0);
    k_sm<<<B, 256, 0, stream>>>(SCT, PAIR, xdst, v12, c0s, out, A2, gb, t, 0);
    k_giup<<<dim3(24, 4, 4), 256, 0, stream>>>(A2, Wbig, GI, xdst);
    k_h1c<<<B, 256, 0, stream>>>(xdst, GI, b_hh, H1P);
    k_ghcs<<<dim3(24, 4, 2), 256, 0, stream>>>(xdst, H1P, W_hh, GHCP);
    k_pairc<<<NWS, 256, 0, stream>>>(wlb, wlL, wlR, GI, GHCP, H1P, w_fc, b_fc, PAIR, SCR);
  }

  // ---- final: h2 = PAIR[b][pos0[b*16]]; attention, scores+loss straight to out ----
  k_qscsel<<<dim3(24, 4, 2), 256, 0, stream>>>(PAIR, SCR, pos0, pos1, wlb, wlL, wlR,
                                               xdst, Gbig, SCT, GI, b_ih, GHCP, b_hh,
                                               1, 1);
  k_sm<<<B, 256, 0, stream>>>(SCT, PAIR, xdst, v12, c0s, out, A2, gb, 15, 1);
}

// Round 15
// 1325.559 us; speedup vs baseline: 1.2073x; 1.0087x over previous
//
#include <hip/hip_runtime.h>

#define B 128
#define S 16
#define E 512
#define R 1000
#define K3 1536
#define NW0 1920   // init worklist: 128 b * 15 pairs
#define NWS 256    // per-step worklist: 128 b * 2 entries
#define NS (B * (R + 1))
#define SCALE 0.04419417382415922f

static __device__ __forceinline__ float sigm(float x) { return 1.f / (1.f + expf(-x)); }

// ---------- block reductions (256 threads) ----------
static __device__ __forceinline__ float brsum(float v, float* sb) {
  int tid = threadIdx.x;
  sb[tid] = v; __syncthreads();
  for (int s = 128; s > 0; s >>= 1) {
    if (tid < s) sb[tid] += sb[tid + s];
    __syncthreads();
  }
  float r = sb[0]; __syncthreads();
  return r;
}
static __device__ __forceinline__ float brmax(float v, float* sb) {
  int tid = threadIdx.x;
  sb[tid] = v; __syncthreads();
  for (int s = 128; s > 0; s >>= 1) {
    if (tid < s) sb[tid] = fmaxf(sb[tid], sb[tid + s]);
    __syncthreads();
  }
  float r = sb[0]; __syncthreads();
  return r;
}
// paired sum reduction: (v1,v2) -> (sb[0], sb2[0])
static __device__ __forceinline__ void brsum2(float v1, float v2, float* sb, float* sb2,
                                              float* o1, float* o2) {
  int tid = threadIdx.x;
  sb[tid] = v1; sb2[tid] = v2; __syncthreads();
  for (int s = 128; s > 0; s >>= 1) {
    if (tid < s) { sb[tid] += sb[tid + s]; sb2[tid] += sb2[tid + s]; }
    __syncthreads();
  }
  *o1 = sb[0]; *o2 = sb2[0]; __syncthreads();
}

#define TILE_FMA \
  _Pragma("unroll") \
  for (int k = 0; k < 16; ++k) { \
    float4 a4 = *(const float4*)&As[k][ty * 4]; \
    float4 w4 = *(const float4*)&Ws[k][tx * 4]; \
    acc[0][0] = fmaf(a4.x, w4.x, acc[0][0]); acc[0][1] = fmaf(a4.x, w4.y, acc[0][1]); \
    acc[0][2] = fmaf(a4.x, w4.z, acc[0][2]); acc[0][3] = fmaf(a4.x, w4.w, acc[0][3]); \
    acc[1][0] = fmaf(a4.y, w4.x, acc[1][0]); acc[1][1] = fmaf(a4.y, w4.y, acc[1][1]); \
    acc[1][2] = fmaf(a4.y, w4.z, acc[1][2]); acc[1][3] = fmaf(a4.y, w4.w, acc[1][3]); \
    acc[2][0] = fmaf(a4.z, w4.x, acc[2][0]); acc[2][1] = fmaf(a4.z, w4.y, acc[2][1]); \
    acc[2][2] = fmaf(a4.z, w4.z, acc[2][2]); acc[2][3] = fmaf(a4.z, w4.w, acc[2][3]); \
    acc[3][0] = fmaf(a4.w, w4.x, acc[3][0]); acc[3][1] = fmaf(a4.w, w4.y, acc[3][1]); \
    acc[3][2] = fmaf(a4.w, w4.z, acc[3][2]); acc[3][3] = fmaf(a4.w, w4.w, acc[3][3]); \
  }

// 32-row-tile inner product: acc[2][4], A in As[16][32], W in Ws[16][64]
#define TILE_FMA32 \
  _Pragma("unroll") \
  for (int k = 0; k < 16; ++k) { \
    float2 a2 = *(const float2*)&As[k][ty * 2]; \
    float4 w4 = *(const float4*)&Ws[k][tx * 4]; \
    acc[0][0] = fmaf(a2.x, w4.x, acc[0][0]); acc[0][1] = fmaf(a2.x, w4.y, acc[0][1]); \
    acc[0][2] = fmaf(a2.x, w4.z, acc[0][2]); acc[0][3] = fmaf(a2.x, w4.w, acc[0][3]); \
    acc[1][0] = fmaf(a2.y, w4.x, acc[1][0]); acc[1][1] = fmaf(a2.y, w4.y, acc[1][1]); \
    acc[1][2] = fmaf(a2.y, w4.z, acc[1][2]); acc[1][3] = fmaf(a2.y, w4.w, acc[1][3]); \
  }

// ---------- generic tiled gemm (standalone body — VGPR~44 codegen) ----------
__global__ __launch_bounds__(256) void k_gemm(const float* __restrict__ A, int lda, int M,
                                              const float* __restrict__ W, int N, int K,
                                              const float* __restrict__ bias, float scale,
                                              float* __restrict__ C, int ldc) {
  __shared__ float As[16][64];
  __shared__ float Ws[16][64];
  int tid = threadIdx.x;
  int mBase = blockIdx.y * 64;
  int nBase = blockIdx.x * 64;
  int tx = tid & 15, ty = tid >> 4;
  int li = tid & 63;
  int lk = (tid >> 6) * 4;
  float acc[4][4] = {{0.f,0.f,0.f,0.f},{0.f,0.f,0.f,0.f},{0.f,0.f,0.f,0.f},{0.f,0.f,0.f,0.f}};
  int m = mBase + li;
  const float* Arow = (m < M) ? (A + (size_t)m * lda) : nullptr;
  int n = nBase + li;
  const float* Wrow = (n < N) ? (W + (size_t)n * K) : nullptr;

  float4 av = Arow ? *(const float4*)(Arow + lk) : make_float4(0.f, 0.f, 0.f, 0.f);
  float4 wv = Wrow ? *(const float4*)(Wrow + lk) : make_float4(0.f, 0.f, 0.f, 0.f);

  for (int k0 = 0; k0 < K; k0 += 16) {
    As[lk + 0][li] = av.x; As[lk + 1][li] = av.y;
    As[lk + 2][li] = av.z; As[lk + 3][li] = av.w;
    Ws[lk + 0][li] = wv.x; Ws[lk + 1][li] = wv.y;
    Ws[lk + 2][li] = wv.z; Ws[lk + 3][li] = wv.w;
    __syncthreads();
    if (k0 + 16 < K) {
      av = Arow ? *(const float4*)(Arow + k0 + 16 + lk) : make_float4(0.f, 0.f, 0.f, 0.f);
      wv = Wrow ? *(const float4*)(Wrow + k0 + 16 + lk) : make_float4(0.f, 0.f, 0.f, 0.f);
    }
    TILE_FMA
    __syncthreads();
  }
#pragma unroll
  for (int r = 0; r < 4; ++r) {
    int mm = mBase + ty * 4 + r;
    if (mm >= M) continue;
#pragma unroll
    for (int c = 0; c < 4; ++c) {
      int nn = nBase + tx * 4 + c;
      if (nn >= N) continue;
      float v = acc[r][c] * scale;
      if (bias) v += bias[nn];
      C[(size_t)mm * ldc + nn] = v;
    }
  }
}

// ---------- dual-output gemm: n<N1 -> W1,C1 ; else W2,C2 ----------
__global__ __launch_bounds__(256) void k_gemmD(const float* __restrict__ A, int lda, int M,
                                               const float* __restrict__ W1, int N1,
                                               const float* __restrict__ b1,
                                               float* __restrict__ C1, int ldc1,
                                               const float* __restrict__ W2, int N2,
                                               float* __restrict__ C2, int ldc2, int K) {
  __shared__ float As[16][64];
  __shared__ float Ws[16][64];
  int tid = threadIdx.x;
  int mBase = blockIdx.y * 64;
  int nBase = blockIdx.x * 64;
  int tx = tid & 15, ty = tid >> 4;
  int li = tid & 63;
  int lk = (tid >> 6) * 4;
  float acc[4][4] = {{0.f,0.f,0.f,0.f},{0.f,0.f,0.f,0.f},{0.f,0.f,0.f,0.f},{0.f,0.f,0.f,0.f}};
  int m = mBase + li;
  const float* Arow = (m < M) ? (A + (size_t)m * lda) : nullptr;
  int n = nBase + li;
  const float* Wrow = nullptr;
  if (n < N1) Wrow = W1 + (size_t)n * K;
  else if (n < N1 + N2) Wrow = W2 + (size_t)(n - N1) * K;

  float4 av = Arow ? *(const float4*)(Arow + lk) : make_float4(0.f, 0.f, 0.f, 0.f);
  float4 wv = Wrow ? *(const float4*)(Wrow + lk) : make_float4(0.f, 0.f, 0.f, 0.f);

  for (int k0 = 0; k0 < K; k0 += 16) {
    As[lk + 0][li] = av.x; As[lk + 1][li] = av.y;
    As[lk + 2][li] = av.z; As[lk + 3][li] = av.w;
    Ws[lk + 0][li] = wv.x; Ws[lk + 1][li] = wv.y;
    Ws[lk + 2][li] = wv.z; Ws[lk + 3][li] = wv.w;
    __syncthreads();
    if (k0 + 16 < K) {
      av = Arow ? *(const float4*)(Arow + k0 + 16 + lk) : make_float4(0.f, 0.f, 0.f, 0.f);
      wv = Wrow ? *(const float4*)(Wrow + k0 + 16 + lk) : make_float4(0.f, 0.f, 0.f, 0.f);
    }
    TILE_FMA
    __syncthreads();
  }
#pragma unroll
  for (int r = 0; r < 4; ++r) {
    int mm = mBase + ty * 4 + r;
    if (mm >= M) continue;
#pragma unroll
    for (int c = 0; c < 4; ++c) {
      int nn = nBase + tx * 4 + c;
      if (nn < N1) {
        float v = acc[r][c];
        if (b1) v += b1[nn];
        C1[(size_t)mm * ldc1 + nn] = v;
      } else if (nn < N1 + N2) {
        C2[(size_t)mm * ldc2 + (nn - N1)] = acc[r][c];
      }
    }
  }
}

// ---------- 64x64 transpose tile (device) ----------
static __device__ void dev_tr64(float (*t)[65], int tid, const float* __restrict__ src,
                                int Cc, float* __restrict__ dst, int ldd, int bx, int by) {
  int tx = tid & 15, ty = tid >> 4;
  int rb = by * 64, cb = bx * 64;
#pragma unroll
  for (int i = 0; i < 4; ++i) {
    int r = rb + ty + i * 16;
    float4 v = *(const float4*)(src + (size_t)r * Cc + cb + tx * 4);
    t[ty + i * 16][tx * 4 + 0] = v.x; t[ty + i * 16][tx * 4 + 1] = v.y;
    t[ty + i * 16][tx * 4 + 2] = v.z; t[ty + i * 16][tx * 4 + 3] = v.w;
  }
  __syncthreads();
#pragma unroll
  for (int i = 0; i < 4; ++i) {
    int c = cb + ty + i * 16;
    float4 v;
    v.x = t[tx * 4 + 0][ty + i * 16]; v.y = t[tx * 4 + 1][ty + i * 16];
    v.z = t[tx * 4 + 2][ty + i * 16]; v.w = t[tx * 4 + 3][ty + i * 16];
    *(float4*)(dst + (size_t)c * ldd + rb + tx * 4) = v;
  }
}

// ---------- setup L1: Wih transpose + initwl + pad + out14 + Mqk NT-gemm + v12/bw/wv3/c0 ----
// blocks: [0,192) Wih->WbigT | [192,200) initwl/out14 | [200,208) pad |
//         [208,272) Mqk = Wq^T@Wk -> Gbig+1000 rows | 272-273 v12 | 274-275 bw |
//         276-277 wv3 | 278 c0s
__global__ __launch_bounds__(256) void k_prep(const float* __restrict__ Wq,
                                              const float* __restrict__ Wk,
                                              const float* __restrict__ Wih,
                                              float* __restrict__ Wbig,
                                              int* __restrict__ pos,
                                              int* __restrict__ wlb,
                                              int* __restrict__ wlL,
                                              int* __restrict__ wlR,
                                              float* __restrict__ outp,
                                              float* __restrict__ Gbig,
                                              const float* __restrict__ bq,
                                              const float* __restrict__ bk,
                                              float* __restrict__ v12,
                                              float* __restrict__ bw,
                                              float* __restrict__ wv3,
                                              float* __restrict__ c0s) {
  __shared__ float t[64][65];
  int blk = blockIdx.x, tid = threadIdx.x;
  if (blk < 192) {
    dev_tr64(t, tid, Wih, E, Wbig + (size_t)1024 * K3, K3, blk & 7, blk >> 3);
  } else if (blk < 200) {
    int idx = (blk - 192) * 256 + tid;
    if (idx < B * 16) pos[idx] = idx & 15;
    if (idx < NW0) {
      wlb[idx] = idx / 15;
      int i = idx % 15;
      wlL[idx] = i;
      wlR[idx] = i + 1;
    }
    if (idx < B) outp[NS + idx * 16 + 14] = 0.f;  // loss col 14 is identically 0
  } else if (blk < 208) {
    int idx = (blk - 200) * 256 + tid;
    for (int i = idx; i < 24 * K3; i += 8 * 256) Wbig[(size_t)1000 * K3 + i] = 0.f;
  } else if (blk < 272) {
    // Mqk[i,f] = sum_e Wq[e,i]*Wk[e,f]  (NT gemm, no transposes needed)
    int j = blk - 208;
    int fT = (j & 7) * 64, iT = (j >> 3) * 64;
    float (*As)[64] = (float(*)[64])&t[0][0];
    float (*Ws)[64] = (float(*)[64])&t[20][0];
    int tx = tid & 15, ty = tid >> 4;
    int li = tid & 63, lk = (tid >> 6) * 4;
    float acc[4][4] = {{0.f,0.f,0.f,0.f},{0.f,0.f,0.f,0.f},{0.f,0.f,0.f,0.f},{0.f,0.f,0.f,0.f}};
    float a0 = Wq[(size_t)(lk + 0) * E + iT + li];
    float a1 = Wq[(size_t)(lk + 1) * E + iT + li];
    float a2 = Wq[(size_t)(lk + 2) * E + iT + li];
    float a3 = Wq[(size_t)(lk + 3) * E + iT + li];
    float w0 = Wk[(size_t)(lk + 0) * E + fT + li];
    float w1 = Wk[(size_t)(lk + 1) * E + fT + li];
    float w2 = Wk[(size_t)(lk + 2) * E + fT + li];
    float w3 = Wk[(size_t)(lk + 3) * E + fT + li];
    for (int e0 = 0; e0 < E; e0 += 16) {
      As[lk + 0][li] = a0; As[lk + 1][li] = a1;
      As[lk + 2][li] = a2; As[lk + 3][li] = a3;
      Ws[lk + 0][li] = w0; Ws[lk + 1][li] = w1;
      Ws[lk + 2][li] = w2; Ws[lk + 3][li] = w3;
      __syncthreads();
      if (e0 + 16 < E) {
        a0 = Wq[(size_t)(e0 + 16 + lk + 0) * E + iT + li];
        a1 = Wq[(size_t)(e0 + 16 + lk + 1) * E + iT + li];
        a2 = Wq[(size_t)(e0 + 16 + lk + 2) * E + iT + li];
        a3 = Wq[(size_t)(e0 + 16 + lk + 3) * E + iT + li];
        w0 = Wk[(size_t)(e0 + 16 + lk + 0) * E + fT + li];
        w1 = Wk[(size_t)(e0 + 16 + lk + 1) * E + fT + li];
        w2 = Wk[(size_t)(e0 + 16 + lk + 2) * E + fT + li];
        w3 = Wk[(size_t)(e0 + 16 + lk + 3) * E + fT + li];
      }
      TILE_FMA
      __syncthreads();
    }
#pragma unroll
    for (int r = 0; r < 4; ++r)
#pragma unroll
      for (int c = 0; c < 4; ++c)
        Gbig[(size_t)(1000 + iT + ty * 4 + r) * E + fT + tx * 4 + c] = acc[r][c];
  } else if (blk < 274) {
    int i = (blk - 272) * 256 + tid;
    float s = 0.f;
    for (int e = 0; e < E; ++e) s += Wq[(size_t)e * E + i] * bk[e] + bq[e] * Wk[(size_t)e * E + i];
    v12[i] = s;
  } else if (blk < 276) {
    int i = (blk - 274) * 256 + tid;
    float s = 0.f;
    for (int e = 0; e < E; ++e) s += bk[e] * Wq[(size_t)e * E + i];
    bw[i] = s;
  } else if (blk < 278) {
    int f = (blk - 276) * 256 + tid;
    float s = 0.f;
    for (int e = 0; e < E; ++e) s += bq[e] * Wk[(size_t)e * E + f];
    wv3[f] = s;
  } else {
    float* sb = &t[0][0];
    float p = 0.f;
    for (int e = tid; e < E; e += 256) p += bq[e] * bk[e];
    float s = brsum(p, sb);
    if (tid == 0) c0s[0] = s;
  }
}

// ---------- setup B: H1V vocab h1 [0,1000) | GI gather [1000,3048) | SCT zero | gb ----------
__global__ __launch_bounds__(256) void k_setupB(const int* __restrict__ tokens,
                                                const float* __restrict__ Wbig,
                                                const float* __restrict__ bih,
                                                const float* __restrict__ bhh,
                                                const float* __restrict__ emb,
                                                const float* __restrict__ wv3,
                                                float* __restrict__ GI,
                                                float* __restrict__ H1V,
                                                float* __restrict__ SCT,
                                                float* __restrict__ gb) {
  int blk = blockIdx.x, tid = threadIdx.x;
  if (blk < 1000) {
    const float* ew = Wbig + (size_t)blk * K3;
    float* h = H1V + (size_t)blk * E;
    for (int e = tid; e < E; e += 256) {
      float g0 = ew[e] + bih[e];
      float g1 = ew[E + e] + bih[E + e];
      float g2 = ew[2 * E + e] + bih[2 * E + e];
      float r = sigm(g0 + bhh[e]);
      float z = sigm(g1 + bhh[E + e]);
      h[e] = (1.f - z) * tanhf(g2 + r * bhh[2 * E + e]);
    }
  } else if (blk < 1000 + B * S) {
    int p = blk - 1000;
    int tok = tokens[p];
    const float4* src = (const float4*)(Wbig + (size_t)tok * K3);
    const float4* bv = (const float4*)bih;
    float4* dst = (float4*)(GI + (size_t)p * K3);
    for (int i = tid; i < K3 / 4; i += 256) {
      float4 a = src[i], b = bv[i];
      dst[i] = make_float4(a.x + b.x, a.y + b.y, a.z + b.z, a.w + b.w);
    }
  } else if (blk < 1000 + B * S + 8) {
    int rb = blk - (1000 + B * S);
    for (int m = rb * 16; m < rb * 16 + 16; ++m) {
      float* r = SCT + (size_t)m * K3;
      for (int n = tid; n < 1512; n += 256) r[n] = 0.f;
    }
  } else {
    int r = (blk - (1000 + B * S + 8)) * 256 + tid;
    if (r < R) {
      const float* er = emb + (size_t)r * E;
      float s = 0.f;
      for (int f = 0; f < E; ++f) s += er[f] * wv3[f];
      gb[r] = s;  // raw: score adds (gb + SP.bw + c0)
    }
  }
}

// ---------- setup pairc: compute PAIR/SCR from vocab tables + gather position caches ----
__global__ __launch_bounds__(256) void k_pairc0(const int* __restrict__ tokens,
                                                const float* __restrict__ GI,
                                                const float* __restrict__ GHCV,
                                                const float* __restrict__ H1V,
                                                const float* __restrict__ wfc,
                                                const float* __restrict__ bfc,
                                                float* __restrict__ PAIR,
                                                float* __restrict__ SCR,
                                                float* __restrict__ H1P,
                                                float* __restrict__ GHCP) {
  __shared__ float sb[256];
  int w = blockIdx.x, tid = threadIdx.x;
  int b = w / 15, i = w % 15;
  int lp = b * 16 + i;
  int tok = tokens[lp];
  const float* gr = GI + (size_t)(lp + 1) * K3;
  const float* gh = GHCV + (size_t)tok * K3;
  const float* h = H1V + (size_t)tok * E;
  float* ghp = GHCP + (size_t)lp * K3;
  float* hp = H1P + (size_t)lp * E;
  float* p = PAIR + (size_t)lp * E;
  float part = 0.f;
  for (int e = tid; e < E; e += 256) {
    float g0 = gh[e], g1 = gh[E + e], g2 = gh[2 * E + e], he = h[e];
    ghp[e] = g0; ghp[E + e] = g1; ghp[2 * E + e] = g2; hp[e] = he;
    float r = sigm(gr[e] + g0);
    float z = sigm(gr[E + e] + g1);
    float n = tanhf(gr[2 * E + e] + r * g2);
    float pv = (1.f - z) * n + z * he;
    p[e] = pv;
    part += pv * wfc[e];
  }
  float d = brsum(part, sb);
  if (tid == 0) SCR[lp] = sigm(d + bfc[0]);
}

// ---------- per-step h1: one block per batch; recompute position xdst[b] ----------
__global__ __launch_bounds__(256) void k_h1c(const int* __restrict__ xdst,
                                             const float* __restrict__ GI,
                                             const float* __restrict__ bhh,
                                             float* __restrict__ H1P) {
  int p = xdst[blockIdx.x], tid = threadIdx.x;
  const float* gi = GI + (size_t)p * K3;
  float* h = H1P + (size_t)p * E;
  for (int e = tid; e < E; e += 256) {
    float r = sigm(gi[e] + bhh[e]);
    float z = sigm(gi[E + e] + bhh[E + e]);
    h[e] = (1.f - z) * tanhf(gi[2 * E + e] + r * bhh[2 * E + e]);
  }
}

// ---------- GHC split-K gemm, 32-row tiles, position-indirect: grid (24, 4, 2) ----------
__global__ __launch_bounds__(256) void k_ghcs(const int* __restrict__ xdst,
                                              const float* __restrict__ H1P,
                                              const float* __restrict__ Whh,
                                              float* __restrict__ GHCP) {
  __shared__ float As[16][32];
  __shared__ float Ws[16][64];
  __shared__ int sp[32];
  int tid = threadIdx.x;
  int nBase = blockIdx.x * 64;
  int mBase = blockIdx.y * 32;
  int kbeg = blockIdx.z * 256;
  if (tid < 32) sp[tid] = xdst[mBase + tid];
  __syncthreads();
  int tx = tid & 15, ty = tid >> 4;
  int ar = tid & 31, ak = (tid >> 5) * 2;
  int li = tid & 63, lk = (tid >> 6) * 4;
  float acc[2][4] = {{0.f,0.f,0.f,0.f},{0.f,0.f,0.f,0.f}};
  const float* Arow = H1P + (size_t)sp[ar] * E + kbeg;
  const float* Wrow = Whh + (size_t)(nBase + li) * E + kbeg;
  float2 av = *(const float2*)(Arow + ak);
  float4 wv = *(const float4*)(Wrow + lk);
  for (int k0 = 0; k0 < 256; k0 += 16) {
    As[ak + 0][ar] = av.x; As[ak + 1][ar] = av.y;
    Ws[lk + 0][li] = wv.x; Ws[lk + 1][li] = wv.y;
    Ws[lk + 2][li] = wv.z; Ws[lk + 3][li] = wv.w;
    __syncthreads();
    if (k0 + 16 < 256) {
      av = *(const float2*)(Arow + k0 + 16 + ak);
      wv = *(const float4*)(Wrow + k0 + 16 + lk);
    }
    TILE_FMA32
    __syncthreads();
  }
#pragma unroll
  for (int r = 0; r < 2; ++r) {
    size_t crow = (size_t)sp[ty * 2 + r] * K3;
#pragma unroll
    for (int c = 0; c < 4; ++c) {
      int nn = nBase + tx * 4 + c;
      atomicAdd(&GHCP[crow + nn], acc[r][c]);
    }
  }
}

// ---------- pair + fc score (position-keyed H1P/GHCP caches) ----------
__global__ __launch_bounds__(256) void k_pairc(const int* __restrict__ wlb,
                                               const int* __restrict__ wlL,
                                               const int* __restrict__ wlR,
                                               const float* __restrict__ GI,
                                               const float* __restrict__ GHCP,
                                               const float* __restrict__ H1P,
                                               const float* __restrict__ wfc,
                                               const float* __restrict__ bfc,
                                               float* __restrict__ PAIR,
                                               float* __restrict__ SCR) {
  __shared__ float sb[256];
  int w = blockIdx.x, tid = threadIdx.x;
  int b = wlb[w], ls = wlL[w], rs = wlR[w];
  int lp = b * 16 + ls;
  const float* gr = GI + (size_t)(b * 16 + rs) * K3;
  const float* gh = GHCP + (size_t)lp * K3;
  const float* h = H1P + (size_t)lp * E;
  float* p = PAIR + (size_t)lp * E;
  float part = 0.f;
  for (int e = tid; e < E; e += 256) {
    float r = sigm(gr[e] + gh[e]);
    float z = sigm(gr[E + e] + gh[E + e]);
    float n = tanhf(gr[2 * E + e] + r * gh[2 * E + e]);
    float pv = (1.f - z) * n + z * h[e];
    p[e] = pv;
    part += pv * wfc[e];
  }
  float d = brsum(part, sb);
  if (tid == 0) SCR[b * 16 + ls] = sigm(d + bfc[0]);
}

// ---------- fused sel + scores split-K gemm, 32-row tiles: grid (24, 4, 2) ----------
// Block (0, y, 0) writes pos/wl/xdst; z==1: x<16 write GI[xdst]=bih (2 rows each),
// x in [16,24) write GHCP[xdst]=bhh (4 rows each).
__global__ __launch_bounds__(256) void k_qscsel(const float* __restrict__ PAIR,
                                                const float* __restrict__ SCR,
                                                const int* __restrict__ pin,
                                                int* __restrict__ pout,
                                                int* __restrict__ wlb,
                                                int* __restrict__ wlL,
                                                int* __restrict__ wlR,
                                                int* __restrict__ xdst,
                                                const float* __restrict__ Gbig,
                                                float* __restrict__ SCT,
                                                float* __restrict__ GI,
                                                const float* __restrict__ bih,
                                                float* __restrict__ GHCP,
                                                const float* __restrict__ bhh,
                                                int P, int finalMode) {
  __shared__ float As[16][32];
  __shared__ float Ws[16][64];
  __shared__ int sxd[32];
  int tid = threadIdx.x;
  int nBase = blockIdx.x * 64;
  int mBase = blockIdx.y * 32;
  int kbeg = blockIdx.z * 256;
  if (tid < 32) {
    int b = mBase + tid;
    if (finalMode) {
      int xr = b * 16 + pin[b * 16];
      sxd[tid] = xr;
      if (blockIdx.x == 0 && blockIdx.z == 0) xdst[b] = xr;
    } else {
      int L = P + 1;
      int lp[16];
      for (int i = 0; i < L; ++i) lp[i] = pin[b * 16 + i];
      float best = -1e30f; int sel = 0;
      for (int i = 0; i < P; ++i) {
        float v = SCR[b * 16 + lp[i]];
        if (v > best) { best = v; sel = i; }
      }
      int r1i = (sel + 2 < L) ? sel + 2 : L - 1;
      int l1 = lp[sel], r1 = lp[r1i];
      int l0 = (sel > 0) ? lp[sel - 1] : l1;
      int r0 = (sel > 0) ? lp[sel] : r1;
      sxd[tid] = b * 16 + l1;
      if (blockIdx.x == 0 && blockIdx.z == 0) {
        wlb[2 * b] = b;     wlL[2 * b] = l0;     wlR[2 * b] = r0;
        wlb[2 * b + 1] = b; wlL[2 * b + 1] = l1; wlR[2 * b + 1] = r1;
        xdst[b] = b * 16 + l1;
        for (int i = 0; i < L - 1; ++i)
          pout[b * 16 + i] = (i <= sel) ? lp[i] : lp[i + 1];
      }
    }
  }
  __syncthreads();
  // Early cache-row inits, off the k_sm/k_h1c critical paths (duplicate-safe writes).
  if (!finalMode && blockIdx.z == 1) {
    if (blockIdx.x < 16) {
#pragma unroll
      for (int r = 0; r < 2; ++r) {
        float* g = GI + (size_t)sxd[blockIdx.x * 2 + r] * K3;
        for (int i = tid; i < K3; i += 256) g[i] = bih[i];
      }
    } else {
#pragma unroll
      for (int r = 0; r < 4; ++r) {
        float* g = GHCP + (size_t)sxd[(blockIdx.x - 16) * 4 + r] * K3;
        for (int i = tid; i < K3; i += 256) g[i] = bhh[i];
      }
    }
  }
  int tx = tid & 15, ty = tid >> 4;
  int ar = tid & 31, ak = (tid >> 5) * 2;
  int li = tid & 63, lk = (tid >> 6) * 4;
  float acc[2][4] = {{0.f,0.f,0.f,0.f},{0.f,0.f,0.f,0.f}};
  const float* Arow = PAIR + (size_t)sxd[ar] * E + kbeg;
  int n = nBase + li;
  const float* Wrow = (n < 1512) ? (Gbig + (size_t)n * E + kbeg) : nullptr;
  float2 av = *(const float2*)(Arow + ak);
  float4 wv = Wrow ? *(const float4*)(Wrow + lk) : make_float4(0.f, 0.f, 0.f, 0.f);
  for (int k0 = 0; k0 < 256; k0 += 16) {
    As[ak + 0][ar] = av.x; As[ak + 1][ar] = av.y;
    Ws[lk + 0][li] = wv.x; Ws[lk + 1][li] = wv.y;
    Ws[lk + 2][li] = wv.z; Ws[lk + 3][li] = wv.w;
    __syncthreads();
    if (k0 + 16 < 256) {
      av = *(const float2*)(Arow + k0 + 16 + ak);
      wv = Wrow ? *(const float4*)(Wrow + k0 + 16 + lk) : make_float4(0.f, 0.f, 0.f, 0.f);
    }
    TILE_FMA32
    __syncthreads();
  }
#pragma unroll
  for (int r = 0; r < 2; ++r) {
    int mm = mBase + ty * 2 + r;
#pragma unroll
    for (int c = 0; c < 4; ++c) {
      int nn = nBase + tx * 4 + c;
      if (nn < 1512) atomicAdd(&SCT[(size_t)mm * K3 + nn], acc[r][c]);
    }
  }
}

// ---------- softmax/entropy + A2 build + SCT re-init (zeros) ----------
// SCT holds RAW dots; score = (SCT + gb_raw + SP.bw + c0)*SCALE.
__global__ __launch_bounds__(256) void k_sm(float* __restrict__ SCT,
                                            const float* __restrict__ PAIR,
                                            const int* __restrict__ xdst,
                                            const float* __restrict__ v12,
                                            const float* __restrict__ bw,
                                            const float* __restrict__ c0s,
                                            float* __restrict__ outp,
                                            float* __restrict__ A2,
                                            const float* __restrict__ gb,
                                            int t, int finalMode) {
  __shared__ float sb[256];
  __shared__ float sb2[256];
  __shared__ float sps[E];
  int b = blockIdx.x, tid = threadIdx.x;
  float* row = SCT + (size_t)b * K3;
  int xr = xdst[b];
  const float* sp = PAIR + (size_t)xr * E;
  for (int i = tid; i < E; i += 256) sps[i] = sp[i];
  __syncthreads();
  // bilinear self-score (Mqk part in cols 1000..1511) + SP.bw shift, one paired reduce
  float part = 0.f, pbw = 0.f;
  for (int i = tid; i < E; i += 256) {
    part += sps[i] * (row[1000 + i] + v12[i]);
    pbw += sps[i] * bw[i];
  }
  float ps, pb;
  brsum2(part, pbw, sb, sb2, &ps, &pb);
  float last = (ps + c0s[0]) * SCALE;
  float shift = pb + c0s[0];
  float s[4];
  float ml = last;
#pragma unroll
  for (int q = 0; q < 4; ++q) {
    int j = tid + q * 256;
    s[q] = (j < 1000) ? (row[j] + gb[j] + shift) * SCALE : -1e30f;
    ml = fmaxf(ml, s[q]);
  }
  float mx = brmax(ml, sb);
  float zp = 0.f, s1p = 0.f;
#pragma unroll
  for (int q = 0; q < 4; ++q) {
    int j = tid + q * 256;
    if (j < 1000) { float e = expf(s[q] - mx); zp += e; s1p += e * s[q]; }
  }
  if (tid == 0) { float e = expf(last - mx); zp += e; s1p += e * last; }
  float z, s1;
  brsum2(zp, s1p, sb, sb2, &z, &s1);
  if (tid == 0) outp[NS + b * 16 + t] = mx + logf(z) - s1 / z;
  if (!finalMode) {
    float inv = 1.f / z;
    float* a = A2 + (size_t)b * K3;
#pragma unroll
    for (int q = 0; q < 4; ++q) {
      int j = tid + q * 256;
      if (j < 1000) a[j] = expf(s[q] - mx) * inv;
    }
    if (tid < 24) a[1000 + tid] = 0.f;
    float pr = expf(last - mx) * inv;
    for (int i = tid; i < E; i += 256) a[1024 + i] = pr * sps[i];
    // re-init SCT row to zeros for the next step's split-K accumulation
    for (int n2 = tid; n2 < 1512; n2 += 256) row[n2] = 0.f;
  } else {
    float* so = outp + (size_t)b * (R + 1);
#pragma unroll
    for (int q = 0; q < 4; ++q) {
      int j = tid + q * 256;
      if (j < 1000) so[j] = s[q];
    }
    if (tid == 0) so[R] = last;
  }
}

// ---------- fused merged+GI gemm, split-K atomic, 32-row tiles, reg-prefetch:
// grid (24,4,4) ----------
__global__ __launch_bounds__(256) void k_giup(const float* __restrict__ A2,
                                              const float* __restrict__ Wbig,
                                              float* __restrict__ GI,
                                              const int* __restrict__ xdst) {
  __shared__ float As[16][32];
  __shared__ float Ws[16][64];
  int tid = threadIdx.x;
  int nBase = blockIdx.x * 64;
  int mBase = blockIdx.y * 32;
  int kbeg = blockIdx.z * 384;
  int kend = kbeg + 384;
  int tx = tid & 15, ty = tid >> 4;
  int ar = tid & 31, ak = (tid >> 5) * 2;
  int li = tid & 63, wr = tid >> 6;
  float acc[2][4] = {{0.f,0.f,0.f,0.f},{0.f,0.f,0.f,0.f}};
  const float* Arow = A2 + (size_t)(mBase + ar) * K3;
  float2 av = *(const float2*)(Arow + kbeg + ak);
  float w0 = Wbig[(size_t)(kbeg + wr * 4 + 0) * K3 + nBase + li];
  float w1 = Wbig[(size_t)(kbeg + wr * 4 + 1) * K3 + nBase + li];
  float w2 = Wbig[(size_t)(kbeg + wr * 4 + 2) * K3 + nBase + li];
  float w3 = Wbig[(size_t)(kbeg + wr * 4 + 3) * K3 + nBase + li];
  for (int k0 = kbeg; k0 < kend; k0 += 16) {
    As[ak + 0][ar] = av.x; As[ak + 1][ar] = av.y;
    Ws[wr * 4 + 0][li] = w0; Ws[wr * 4 + 1][li] = w1;
    Ws[wr * 4 + 2][li] = w2; Ws[wr * 4 + 3][li] = w3;
    __syncthreads();
    if (k0 + 16 < kend) {  // register prefetch of next tile
      av = *(const float2*)(Arow + k0 + 16 + ak);
      w0 = Wbig[(size_t)(k0 + 16 + wr * 4 + 0) * K3 + nBase + li];
      w1 = Wbig[(size_t)(k0 + 16 + wr * 4 + 1) * K3 + nBase + li];
      w2 = Wbig[(size_t)(k0 + 16 + wr * 4 + 2) * K3 + nBase + li];
      w3 = Wbig[(size_t)(k0 + 16 + wr * 4 + 3) * K3 + nBase + li];
    }
    TILE_FMA32
    __syncthreads();
  }
#pragma unroll
  for (int r = 0; r < 2; ++r) {
    int mm = mBase + ty * 2 + r;
    size_t crow = (size_t)xdst[mm] * K3;
#pragma unroll
    for (int c = 0; c < 4; ++c) {
      int nn = nBase + tx * 4 + c;
      atomicAdd(&GI[crow + nn], acc[r][c]);
    }
  }
}

extern "C" void kernel_launch(void* const* d_in, const int* in_sizes, int n_in,
                              void* d_out, int out_size, void* d_ws, size_t ws_size,
                              hipStream_t stream) {
  (void)in_sizes; (void)n_in; (void)out_size; (void)ws_size;
  const int* tokens = (const int*)d_in[0];
  const float* emb = (const float*)d_in[1];
  const float* W_ih = (const float*)d_in[2];
  const float* W_hh = (const float*)d_in[3];
  const float* b_ih = (const float*)d_in[4];
  const float* b_hh = (const float*)d_in[5];
  const float* w_fc = (const float*)d_in[6];
  const float* b_fc = (const float*)d_in[7];
  const float* Wq = (const float*)d_in[8];
  const float* bq = (const float*)d_in[9];
  const float* Wk = (const float*)d_in[10];
  const float* bk = (const float*)d_in[11];
  float* out = (float*)d_out;

  float* ws = (float*)d_ws;
  size_t o = 0;
  float* GI = ws + o;    o += (size_t)B * S * K3;
  float* GHCP = ws + o;  o += (size_t)B * S * K3;   // position-keyed W_hh@h1 cache
  float* H1P = ws + o;   o += (size_t)B * S * E;    // position-keyed h1 cache
  float* PAIR = ws + o;  o += (size_t)B * S * E;
  float* Wbig = ws + o;  o += (size_t)K3 * K3;      // [EW(1000) | 0(24) | W_ih^T(512)] k-major
  float* Gbig = ws + o;  o += (size_t)1512 * E;     // [G2(1000) ; Mqk(512)]
  float* H1V = ws + o;   o += (size_t)1024 * E;     // vocab h1 table
  float* GHCV = ws + o;  o += (size_t)1024 * K3;    // vocab W_hh@h1 table (+bhh)
  float* SCT = ws + o;   o += (size_t)B * K3;
  float* A2 = ws + o;    o += (size_t)B * K3;
  float* gb = ws + o;    o += 1024;
  float* v12 = ws + o;   o += 512;
  float* bw = ws + o;    o += 512;
  float* wv3 = ws + o;   o += 512;
  float* c0s = ws + o;   o += 16;
  float* SCR = ws + o;   o += B * 16;
  int* pos0 = (int*)(ws + o); o += B * 16;
  int* pos1 = (int*)(ws + o); o += B * 16;
  int* wlb = (int*)(ws + o);  o += NW0;
  int* wlL = (int*)(ws + o);  o += NW0;
  int* wlR = (int*)(ws + o);  o += NW0;
  int* xdst = (int*)(ws + o); o += B;

  // ---- setup: 5 launches ----
  // L1: Wih transpose + initwl + pad + Mqk (NT, direct from Wq/Wk) + v12/bw/wv3/c0
  k_prep<<<279, 256, 0, stream>>>(Wq, Wk, W_ih, Wbig, pos0, wlb, wlL, wlR, out,
                                  Gbig, bq, bk, v12, bw, wv3, c0s);
  // L2: ONE pass over emb -> EW (Wbig) and G2 = emb@Mqk^T (Gbig rows 0..999)
  k_gemmD<<<dim3(32, 16), 256, 0, stream>>>(emb, E, R, W_ih, K3, nullptr, Wbig, K3,
                                            Gbig + (size_t)1000 * E, 512, Gbig, E, E);
  // L3: vocab h1 table + GI gather + SCT zero + gb = emb.wv3
  k_setupB<<<1000 + B * S + 8 + 4, 256, 0, stream>>>(tokens, Wbig, b_ih, b_hh, emb,
                                                     wv3, GI, H1V, SCT, gb);
  // L4: GHCV = H1V @ W_hh^T + bhh (vocab domain: M=1000, half the old work)
  k_gemm<<<dim3(24, 16), 256, 0, stream>>>(H1V, E, 1000, W_hh, K3, E, b_hh, 1.f,
                                           GHCV, K3);
  // L5: setup pairc from vocab tables; gathers position caches H1P/GHCP
  k_pairc0<<<NW0, 256, 0, stream>>>(tokens, GI, GHCV, H1V, w_fc, b_fc, PAIR, SCR,
                                    H1P, GHCP);

  // ---- 14 merge steps, 6 kernels each; only position xdst's h1/GHC recomputed ----
  for (int t = 0; t < 14; ++t) {
    int* pin = (t & 1) ? pos1 : pos0;
    int* pout = (t & 1) ? pos0 : pos1;
    k_qscsel<<<dim3(24, 4, 2), 256, 0, stream>>>(PAIR, SCR, pin, pout, wlb, wlL, wlR,
                                                 xdst, Gbig, SCT, GI, b_ih, GHCP, b_hh,
                                                 15 - t, 0);
    k_sm<<<B, 256, 0, stream>>>(SCT, PAIR, xdst, v12, bw, c0s, out, A2, gb, t, 0);
    k_giup<<<dim3(24, 4, 4), 256, 0, stream>>>(A2, Wbig, GI, xdst);
    k_h1c<<<B, 256, 0, stream>>>(xdst, GI, b_hh, H1P);
    k_ghcs<<<dim3(24, 4, 2), 256, 0, stream>>>(xdst, H1P, W_hh, GHCP);
    k_pairc<<<NWS, 256, 0, stream>>>(wlb, wlL, wlR, GI, GHCP, H1P, w_fc, b_fc, PAIR, SCR);
  }

  // ---- final: h2 = PAIR[b][pos0[b*16]]; attention, scores+loss straight to out ----
  k_qscsel<<<dim3(24, 4, 2), 256, 0, stream>>>(PAIR, SCR, pos0, pos1, wlb, wlL, wlR,
                                               xdst, Gbig, SCT, GI, b_ih, GHCP, b_hh,
                                               1, 1);
  k_sm<<<B, 256, 0, stream>>>(SCT, PAIR, xdst, v12, bw, c0s, out, A2, gb, 15, 1);
}